// Round 1
// baseline (1198.814 us; speedup 1.0000x reference)
//
#include <hip/hip_runtime.h>
#include <math.h>

namespace {

constexpr int Bb = 8;
constexpr int Ss = 2048;
constexpr int Dd = 1024;
constexpr int Cc = 16;            // s-chunks for scans / column reductions
constexpr int Sc = Ss / Cc;       // 128
constexpr int Tb = 256;
constexpr float INV_SCALE = 0.03125f;  // 1/sqrt(1024)

// gelu(x, exact) + 1
__device__ __forceinline__ float fm_act(float x) {
  return fmaf(0.5f * x, 1.0f + erff(x * 0.70710678118654752f), 1.0f);
}

__device__ __forceinline__ float blockSum(float v) {
  __shared__ float wsm[Tb / 64];
  for (int off = 32; off > 0; off >>= 1) v += __shfl_down(v, off, 64);
  const int lane = threadIdx.x & 63;
  const int w = threadIdx.x >> 6;
  __syncthreads();
  if (lane == 0) wsm[w] = v;
  __syncthreads();
  return wsm[0] + wsm[1] + wsm[2] + wsm[3];
}

__global__ __launch_bounds__(Tb) void k_fill(float* p, int n, float v) {
  int i = blockIdx.x * Tb + threadIdx.x;
  if (i < n) p[i] = v;
}

// gather emb rows + per-chunk column sums
__global__ __launch_bounds__(Tb) void k_gather_csum(const int* __restrict__ tok,
    const float* __restrict__ emb, float* __restrict__ X, float* __restrict__ cs) {
  const int d = blockIdx.x * Tb + threadIdx.x;
  const int b = blockIdx.y;
  const int c = blockIdx.z;
  const int s0 = c * Sc;
  const int* tp = tok + (size_t)b * Ss + s0;
  float* xp = X + ((size_t)b * Ss + s0) * Dd + d;
  float sum = 0.f;
  for (int i = 0; i < Sc; ++i) {
    float v = emb[(size_t)tp[i] * Dd + d];
    xp[(size_t)i * Dd] = v;
    sum += v;
  }
  cs[((size_t)b * Cc + c) * Dd + d] = sum;
}

// per-chunk column sums of an existing buffer
__global__ __launch_bounds__(Tb) void k_csum(const float* __restrict__ X, float* __restrict__ cs) {
  const int d = blockIdx.x * Tb + threadIdx.x;
  const int b = blockIdx.y;
  const int c = blockIdx.z;
  const int s0 = c * Sc;
  const float* xp = X + ((size_t)b * Ss + s0) * Dd + d;
  float sum = 0.f;
  for (int i = 0; i < Sc; ++i) sum += xp[(size_t)i * Dd];
  cs[((size_t)b * Cc + c) * Dd + d] = sum;
}

// chunked inclusive scan: writes CTX, accumulates e = sum_s x*ctx (gds scalar),
// optionally writes the final running value (column total) to `last`.
__global__ __launch_bounds__(Tb) void k_scan(const float* __restrict__ X, const float* __restrict__ cs,
    float* __restrict__ CTX, float* __restrict__ eacc, float* __restrict__ last) {
  const int d = blockIdx.x * Tb + threadIdx.x;
  const int b = blockIdx.y;
  const int c = blockIdx.z;
  float off = 0.f;
  for (int cc2 = 0; cc2 < c; ++cc2) off += cs[((size_t)b * Cc + cc2) * Dd + d];
  const int s0 = c * Sc;
  const float* xp = X + ((size_t)b * Ss + s0) * Dd + d;
  float* cp = CTX + ((size_t)b * Ss + s0) * Dd + d;
  float run = off, e = 0.f;
  for (int i = 0; i < Sc; ++i) {
    float v = xp[(size_t)i * Dd];
    run += v;
    cp[(size_t)i * Dd] = run;
    e = fmaf(v, run, e);
  }
  atomicAdd(&eacc[b * Dd + d], e);
  if (last && c == Cc - 1) last[b * Dd + d] = run;
}

// self-attn pass1: ecol = sum_s fm(qs*Q)*fm(K); track min/max of qf (qf>0 always)
__global__ __launch_bounds__(Tb) void k_attn_p1(const float* __restrict__ Q, const float* __restrict__ qs,
    const float* __restrict__ Kb, float* __restrict__ ecol, float* __restrict__ qmn, float* __restrict__ qmx) {
  const int d = blockIdx.x * Tb + threadIdx.x;
  const int b = blockIdx.y;
  const int c = blockIdx.z;
  const int j = b * Dd + d;
  const float qscale = qs ? qs[j] : 1.f;
  const int s0 = c * Sc;
  const float* qp = Q + ((size_t)b * Ss + s0) * Dd + d;
  const float* kp = Kb + ((size_t)b * Ss + s0) * Dd + d;
  float e = 0.f, mn = 3.0e38f, mx = 0.f;
  for (int i = 0; i < Sc; ++i) {
    float qf = fm_act(qscale * qp[(size_t)i * Dd]);
    float kf = fm_act(kp[(size_t)i * Dd]);
    e = fmaf(qf, kf, e);
    mn = fminf(mn, qf);
    mx = fmaxf(mx, qf);
  }
  atomicAdd(&ecol[j], e);
  atomicMin(reinterpret_cast<int*>(qmn) + j, __float_as_int(mn));
  atomicMax(reinterpret_cast<int*>(qmx) + j, __float_as_int(mx));
}

// self-attn pass2: T = exp(ec*qf/scale - M) * (vs * Q); accumulate sumexp
__global__ __launch_bounds__(Tb) void k_attn_p2(const float* __restrict__ Q, const float* __restrict__ qs,
    const float* __restrict__ vs, const float* __restrict__ ecol, const float* __restrict__ qmn,
    const float* __restrict__ qmx, float* __restrict__ T, float* __restrict__ se) {
  const int d = blockIdx.x * Tb + threadIdx.x;
  const int b = blockIdx.y;
  const int c = blockIdx.z;
  const int j = b * Dd + d;
  const float qscale = qs ? qs[j] : 1.f;
  const float vscale = vs ? vs[j] : 1.f;
  const float ec = ecol[j];
  const float M = (ec >= 0.f ? ec * qmx[j] : ec * qmn[j]) * INV_SCALE;
  const float ei = ec * INV_SCALE;
  const int s0 = c * Sc;
  const float* qp = Q + ((size_t)b * Ss + s0) * Dd + d;
  float* tp = T + ((size_t)b * Ss + s0) * Dd + d;
  float sum = 0.f;
  for (int i = 0; i < Sc; ++i) {
    float x = qp[(size_t)i * Dd];
    float qf = fm_act(qscale * x);
    float p = expf(fmaf(ei, qf, -M));
    sum += p;
    tp[(size_t)i * Dd] = p * vscale * x;
  }
  atomicAdd(&se[j], sum);
}

// cross-attn pass1: colsum of qf, min/max qf
__global__ __launch_bounds__(Tb) void k_cross_p1(const float* __restrict__ Q,
    float* __restrict__ csq, float* __restrict__ qmn, float* __restrict__ qmx) {
  const int d = blockIdx.x * Tb + threadIdx.x;
  const int b = blockIdx.y;
  const int c = blockIdx.z;
  const int j = b * Dd + d;
  const int s0 = c * Sc;
  const float* qp = Q + ((size_t)b * Ss + s0) * Dd + d;
  float sum = 0.f, mn = 3.0e38f, mx = 0.f;
  for (int i = 0; i < Sc; ++i) {
    float qf = fm_act(qp[(size_t)i * Dd]);
    sum += qf;
    mn = fminf(mn, qf);
    mx = fmaxf(mx, qf);
  }
  atomicAdd(&csq[j], sum);
  atomicMin(reinterpret_cast<int*>(qmn) + j, __float_as_int(mn));
  atomicMax(reinterpret_cast<int*>(qmx) + j, __float_as_int(mx));
}

// cross-attn pass2: ec = fm(k2)*colsum(qf); T = exp(ec*qf/scale - M); sumexp
__global__ __launch_bounds__(Tb) void k_cross_p2(const float* __restrict__ Q, const float* __restrict__ k2,
    const float* __restrict__ csq, const float* __restrict__ qmn, const float* __restrict__ qmx,
    float* __restrict__ T, float* __restrict__ se) {
  const int d = blockIdx.x * Tb + threadIdx.x;
  const int b = blockIdx.y;
  const int c = blockIdx.z;
  const int j = b * Dd + d;
  const float ec = fm_act(k2[j]) * csq[j];
  const float M = (ec >= 0.f ? ec * qmx[j] : ec * qmn[j]) * INV_SCALE;
  const float ei = ec * INV_SCALE;
  const int s0 = c * Sc;
  const float* qp = Q + ((size_t)b * Ss + s0) * Dd + d;
  float* tp = T + ((size_t)b * Ss + s0) * Dd + d;
  float sum = 0.f;
  for (int i = 0; i < Sc; ++i) {
    float qf = fm_act(qp[(size_t)i * Dd]);
    float p = expf(fmaf(ei, qf, -M));
    sum += p;
    tp[(size_t)i * Dd] = p;
  }
  atomicAdd(&se[j], sum);
}

// LayerNorm over D of ( T/dv [*ml] + [rs*]Rsd ), writes Y (may alias Rsd: each
// thread reads only its own elements before writing them)
__global__ __launch_bounds__(Tb) void k_ln(const float* __restrict__ T, const float* __restrict__ dv,
    const float* __restrict__ ml, const float* Rsd, const float* __restrict__ rs,
    const float* __restrict__ g, const float* __restrict__ bt, float* Y) {
  const int row = blockIdx.x;          // b*Ss + s
  const int b = row >> 11;             // row / 2048
  const size_t base = (size_t)row * Dd;
  const int t = threadIdx.x;
  float vals[4];
  float sum = 0.f;
#pragma unroll
  for (int k = 0; k < 4; ++k) {
    const int d = t + k * Tb;
    const int j = b * Dd + d;
    float a = T[base + d] / dv[j];
    if (ml) a *= ml[j];
    float r = Rsd[base + d];
    if (rs) r *= rs[j];
    a += r;
    vals[k] = a;
    sum += a;
  }
  sum = blockSum(sum);
  const float mu = sum * (1.0f / Dd);
  float vs2 = 0.f;
#pragma unroll
  for (int k = 0; k < 4; ++k) { float dlt = vals[k] - mu; vs2 = fmaf(dlt, dlt, vs2); }
  vs2 = blockSum(vs2);
  const float inv = rsqrtf(vs2 * (1.0f / Dd) + 1e-5f);
#pragma unroll
  for (int k = 0; k < 4; ++k) {
    const int d = t + k * Tb;
    Y[base + d] = fmaf((vals[k] - mu) * inv, g[d], bt[d]);
  }
}

// column sums over S (atomic accumulate into (B,D))
__global__ __launch_bounds__(Tb) void k_colsum(const float* __restrict__ X, float* __restrict__ acc) {
  const int d = blockIdx.x * Tb + threadIdx.x;
  const int b = blockIdx.y;
  const int c = blockIdx.z;
  const int s0 = c * Sc;
  const float* xp = X + ((size_t)b * Ss + s0) * Dd + d;
  float sum = 0.f;
  for (int i = 0; i < Sc; ++i) sum += xp[(size_t)i * Dd];
  atomicAdd(&acc[b * Dd + d], sum);
}

// out[b,o] = (pooled[b,:]/S) @ Wc[:,o] + bc[o]   (O=2)
__global__ __launch_bounds__(Tb) void k_final(const float* __restrict__ pooled, const float* __restrict__ Wc,
    const float* __restrict__ bc, float* __restrict__ out) {
  const int o = blockIdx.x;
  const int b = blockIdx.y;
  float s = 0.f;
  for (int d = threadIdx.x; d < Dd; d += Tb) s = fmaf(pooled[b * Dd + d], Wc[d * 2 + o], s);
  s = blockSum(s);
  if (threadIdx.x == 0) out[b * 2 + o] = s * (1.0f / Ss) + bc[o];
}

}  // namespace

extern "C" void kernel_launch(void* const* d_in, const int* in_sizes, int n_in,
                              void* d_out, int out_size, void* d_ws, size_t ws_size,
                              hipStream_t stream) {
  (void)in_sizes; (void)n_in; (void)out_size; (void)ws_size;
  const int* src = (const int*)d_in[0];
  const int* trg = (const int*)d_in[1];
  const float* emb = (const float*)d_in[2];
  const float* enc_g = (const float*)d_in[3];
  const float* enc_b = (const float*)d_in[4];
  const float* dec_ng = (const float*)d_in[5];
  const float* dec_nb = (const float*)d_in[6];
  const float* dec_tg = (const float*)d_in[7];
  const float* dec_tb = (const float*)d_in[8];
  const float* Wc = (const float*)d_in[9];
  const float* bc = (const float*)d_in[10];
  float* out = (float*)d_out;

  float* ws = (float*)d_ws;
  const size_t TEN = (size_t)Bb * Ss * Dd;          // 16M floats
  float* A0 = ws;
  float* A1 = ws + TEN;
  float* cs = ws + 2 * TEN;                         // B*C*D chunk sums
  float* sm = cs + (size_t)Bb * Cc * Dd;            // small vectors, 31 x B*D
  const int BD = Bb * Dd;
  auto SV = [&](int i) { return sm + (size_t)i * BD; };
  // slots: 0..3 e-scales (e0,e1,e0d,e1d); 4..7 ecol; 8..13 qmn; 14..19 qmx;
  //        20..25 sumexp; 26..27 cross colsum(qf); 28 enc_ctx; 29 v2; 30 pooled

  hipMemsetAsync(sm, 0, (size_t)31 * BD * sizeof(float), stream);
  k_fill<<<dim3((6 * BD + Tb - 1) / Tb), Tb, 0, stream>>>(SV(8), 6 * BD, 3.0e38f);

  dim3 gC(Dd / Tb, Bb, Cc);
  const int LNG = Bb * Ss;

  // ================= encoder =================
  k_gather_csum<<<gC, Tb, 0, stream>>>(src, emb, A0, cs);                 // X -> A0
  k_scan<<<gC, Tb, 0, stream>>>(A0, cs, A1, SV(0), nullptr);              // CTX -> A1, e0
  k_attn_p1<<<gC, Tb, 0, stream>>>(A0, SV(0), A1, SV(4), SV(8), SV(14));
  k_attn_p2<<<gC, Tb, 0, stream>>>(A0, SV(0), SV(0), SV(4), SV(8), SV(14), A1, SV(20)); // T -> A1
  k_ln<<<LNG, Tb, 0, stream>>>(A1, SV(20), nullptr, A0, SV(0), enc_g, enc_b, A0);       // OUT1 -> A0
  k_csum<<<gC, Tb, 0, stream>>>(A0, cs);
  k_scan<<<gC, Tb, 0, stream>>>(A0, cs, A1, SV(1), SV(28));               // CTX1 -> A1, e1, enc_ctx
  k_attn_p1<<<gC, Tb, 0, stream>>>(A0, nullptr, A1, SV(5), SV(9), SV(15));
  k_attn_p2<<<gC, Tb, 0, stream>>>(A0, nullptr, SV(1), SV(5), SV(9), SV(15), A1, SV(21));
  k_ln<<<LNG, Tb, 0, stream>>>(A1, SV(21), nullptr, A0, nullptr, enc_g + Dd, enc_b + Dd, A0); // enc_out -> A0
  k_colsum<<<gC, Tb, 0, stream>>>(A0, SV(29));                            // v2

  // ================= decoder =================
  k_gather_csum<<<gC, Tb, 0, stream>>>(trg, emb, A0, cs);                 // XE -> A0
  k_scan<<<gC, Tb, 0, stream>>>(A0, cs, A1, SV(2), nullptr);              // CTXd -> A1, e0d
  k_attn_p1<<<gC, Tb, 0, stream>>>(A0, SV(2), A1, SV(6), SV(10), SV(16));
  k_attn_p2<<<gC, Tb, 0, stream>>>(A0, SV(2), SV(2), SV(6), SV(10), SV(16), A1, SV(22));
  k_ln<<<LNG, Tb, 0, stream>>>(A1, SV(22), nullptr, A0, SV(2), dec_ng, dec_nb, A0);     // q0 -> A0
  k_cross_p1<<<gC, Tb, 0, stream>>>(A0, SV(26), SV(12), SV(18));
  k_cross_p2<<<gC, Tb, 0, stream>>>(A0, SV(28), SV(26), SV(12), SV(18), A1, SV(24));
  k_ln<<<LNG, Tb, 0, stream>>>(A1, SV(24), SV(29), A0, nullptr, dec_tg, dec_tb, A0);    // x1 -> A0
  k_csum<<<gC, Tb, 0, stream>>>(A0, cs);
  k_scan<<<gC, Tb, 0, stream>>>(A0, cs, A1, SV(3), nullptr);              // CTXd1 -> A1, e1d
  k_attn_p1<<<gC, Tb, 0, stream>>>(A0, nullptr, A1, SV(7), SV(11), SV(17));
  k_attn_p2<<<gC, Tb, 0, stream>>>(A0, nullptr, SV(3), SV(7), SV(11), SV(17), A1, SV(23));
  k_ln<<<LNG, Tb, 0, stream>>>(A1, SV(23), nullptr, A0, nullptr, dec_ng + Dd, dec_nb + Dd, A0); // q1 -> A0
  k_cross_p1<<<gC, Tb, 0, stream>>>(A0, SV(27), SV(13), SV(19));
  k_cross_p2<<<gC, Tb, 0, stream>>>(A0, SV(28), SV(27), SV(13), SV(19), A1, SV(25));
  k_ln<<<LNG, Tb, 0, stream>>>(A1, SV(25), SV(29), A0, nullptr, dec_tg + Dd, dec_tb + Dd, A0); // x2 -> A0
  k_colsum<<<gC, Tb, 0, stream>>>(A0, SV(30));                            // pooled (unnormalized)
  k_final<<<dim3(2, Bb), Tb, 0, stream>>>(SV(30), Wc, bc, out);
}

// Round 2
// 714.768 us; speedup vs baseline: 1.6772x; 1.6772x over previous
//
#include <hip/hip_runtime.h>
#include <math.h>

namespace {

constexpr int Bb = 8;
constexpr int Ss = 2048;
constexpr int Dd = 1024;
constexpr int D4 = Dd / 4;        // float4 per row = 256
constexpr int NC = 128;           // s-chunks
constexpr int Sc2 = Ss / NC;      // 16 rows per chunk
constexpr int Tb = 256;
constexpr float INV_SCALE = 0.03125f;  // 1/sqrt(1024)
constexpr float BIG = 3.0e38f;

// gelu(x, exact) + 1
__device__ __forceinline__ float fm_act(float x) {
  return fmaf(0.5f * x, 1.0f + erff(x * 0.70710678118654752f), 1.0f);
}

__device__ __forceinline__ float4 f4(float v) { return make_float4(v, v, v, v); }
__device__ __forceinline__ float4 add4(float4 a, float4 b) {
  return make_float4(a.x + b.x, a.y + b.y, a.z + b.z, a.w + b.w);
}
__device__ __forceinline__ float4 mul4(float4 a, float4 b) {
  return make_float4(a.x * b.x, a.y * b.y, a.z * b.z, a.w * b.w);
}
__device__ __forceinline__ float4 fma4(float4 a, float4 b, float4 c) {
  return make_float4(fmaf(a.x, b.x, c.x), fmaf(a.y, b.y, c.y), fmaf(a.z, b.z, c.z), fmaf(a.w, b.w, c.w));
}
__device__ __forceinline__ float4 min4(float4 a, float4 b) {
  return make_float4(fminf(a.x, b.x), fminf(a.y, b.y), fminf(a.z, b.z), fminf(a.w, b.w));
}
__device__ __forceinline__ float4 max4(float4 a, float4 b) {
  return make_float4(fmaxf(a.x, b.x), fmaxf(a.y, b.y), fmaxf(a.z, b.z), fmaxf(a.w, b.w));
}
__device__ __forceinline__ float4 fm4(float4 x) {
  return make_float4(fm_act(x.x), fm_act(x.y), fm_act(x.z), fm_act(x.w));
}
__device__ __forceinline__ float4 ld4(const float* p, size_t j4) {
  return reinterpret_cast<const float4*>(p)[j4];
}
__device__ __forceinline__ void st4(float* p, size_t j4, float4 v) {
  reinterpret_cast<float4*>(p)[j4] = v;
}
// exp(ei*qf - M) componentwise
__device__ __forceinline__ float4 pexp4(float4 ei, float4 qf, float4 M) {
  return make_float4(expf(fmaf(ei.x, qf.x, -M.x)), expf(fmaf(ei.y, qf.y, -M.y)),
                     expf(fmaf(ei.z, qf.z, -M.z)), expf(fmaf(ei.w, qf.w, -M.w)));
}

__device__ __forceinline__ float blockSum(float v) {
  __shared__ float wsm[Tb / 64];
  for (int off = 32; off > 0; off >>= 1) v += __shfl_down(v, off, 64);
  const int lane = threadIdx.x & 63;
  const int w = threadIdx.x >> 6;
  __syncthreads();
  if (lane == 0) wsm[w] = v;
  __syncthreads();
  return wsm[0] + wsm[1] + wsm[2] + wsm[3];
}

// ---------- big column-pass kernels: grid(NC, B), 256 thr, thread t = float4 at d=4t ----------

// gather emb rows, write X, per-chunk column sums + local gds partial
__global__ __launch_bounds__(Tb) void k_gather_cs(const int* __restrict__ tok, const float* __restrict__ emb,
    float* __restrict__ X, float* __restrict__ cs, float* __restrict__ el) {
  const int t = threadIdx.x, c = blockIdx.x, b = blockIdx.y;
  const int* tp = tok + b * Ss + c * Sc2;
  float4* xp = reinterpret_cast<float4*>(X) + ((size_t)(b * Ss + c * Sc2)) * D4 + t;
  const float4* ep = reinterpret_cast<const float4*>(emb);
  float4 run = f4(0.f), e = f4(0.f);
#pragma unroll 4
  for (int i = 0; i < Sc2; ++i) {
    float4 v = ep[(size_t)tp[i] * D4 + t];
    xp[(size_t)i * D4] = v;
    run = add4(run, v);
    e = fma4(v, run, e);
  }
  const size_t idx = ((size_t)b * NC + c) * D4 + t;
  st4(cs, idx, run);
  st4(el, idx, e);
}

// per-chunk column sums + local gds partial of existing X
__global__ __launch_bounds__(Tb) void k_cs(const float* __restrict__ X, float* __restrict__ cs,
    float* __restrict__ el) {
  const int t = threadIdx.x, c = blockIdx.x, b = blockIdx.y;
  const float4* xp = reinterpret_cast<const float4*>(X) + ((size_t)(b * Ss + c * Sc2)) * D4 + t;
  float4 run = f4(0.f), e = f4(0.f);
#pragma unroll 4
  for (int i = 0; i < Sc2; ++i) {
    float4 v = xp[(size_t)i * D4];
    run = add4(run, v);
    e = fma4(v, run, e);
  }
  const size_t idx = ((size_t)b * NC + c) * D4 + t;
  st4(cs, idx, run);
  st4(el, idx, e);
}

// self-attn p1: recompute ctx from off + running sum; partial ecol & qf min/max per chunk
__global__ __launch_bounds__(Tb) void k_p1(const float* __restrict__ X, const float* __restrict__ qs,
    const float* __restrict__ off, float* __restrict__ pe, float* __restrict__ pmn, float* __restrict__ pmx) {
  const int t = threadIdx.x, c = blockIdx.x, b = blockIdx.y;
  const size_t idx = ((size_t)b * NC + c) * D4 + t;
  float4 run = ld4(off, idx);
  const float4 q4 = qs ? ld4(qs, (size_t)b * D4 + t) : f4(1.f);
  const float4* xp = reinterpret_cast<const float4*>(X) + ((size_t)(b * Ss + c * Sc2)) * D4 + t;
  float4 e = f4(0.f), mn = f4(BIG), mx = f4(0.f);
#pragma unroll 4
  for (int i = 0; i < Sc2; ++i) {
    float4 x = xp[(size_t)i * D4];
    run = add4(run, x);
    float4 qf = fm4(mul4(q4, x));
    float4 kf = fm4(run);
    e = fma4(qf, kf, e);
    mn = min4(mn, qf);
    mx = max4(mx, qf);
  }
  st4(pe, idx, e);
  st4(pmn, idx, mn);
  st4(pmx, idx, mx);
}

// p2: partial sumexp per chunk (works for self [qs] and cross [qs=null])
__global__ __launch_bounds__(Tb) void k_p2(const float* __restrict__ X, const float* __restrict__ qs,
    const float* __restrict__ ei, const float* __restrict__ Mv, float* __restrict__ ps) {
  const int t = threadIdx.x, c = blockIdx.x, b = blockIdx.y;
  const size_t j4 = (size_t)b * D4 + t;
  const float4 q4 = qs ? ld4(qs, j4) : f4(1.f);
  const float4 e4 = ld4(ei, j4);
  const float4 M4 = ld4(Mv, j4);
  const float4* xp = reinterpret_cast<const float4*>(X) + ((size_t)(b * Ss + c * Sc2)) * D4 + t;
  float4 s = f4(0.f);
#pragma unroll 4
  for (int i = 0; i < Sc2; ++i) {
    float4 x = xp[(size_t)i * D4];
    float4 qf = fm4(mul4(q4, x));
    s = add4(s, pexp4(e4, qf, M4));
  }
  st4(ps, ((size_t)b * NC + c) * D4 + t, s);
}

// cross-attn p1: partial colsum(fm(x)) + min/max
__global__ __launch_bounds__(Tb) void k_xp1(const float* __restrict__ X, float* __restrict__ pe,
    float* __restrict__ pmn, float* __restrict__ pmx) {
  const int t = threadIdx.x, c = blockIdx.x, b = blockIdx.y;
  const float4* xp = reinterpret_cast<const float4*>(X) + ((size_t)(b * Ss + c * Sc2)) * D4 + t;
  float4 s = f4(0.f), mn = f4(BIG), mx = f4(0.f);
#pragma unroll 4
  for (int i = 0; i < Sc2; ++i) {
    float4 qf = fm4(xp[(size_t)i * D4]);
    s = add4(s, qf);
    mn = min4(mn, qf);
    mx = max4(mx, qf);
  }
  const size_t idx = ((size_t)b * NC + c) * D4 + t;
  st4(pe, idx, s);
  st4(pmn, idx, mn);
  st4(pmx, idx, mx);
}

// partial column sums
__global__ __launch_bounds__(Tb) void k_colp(const float* __restrict__ X, float* __restrict__ pp) {
  const int t = threadIdx.x, c = blockIdx.x, b = blockIdx.y;
  const float4* xp = reinterpret_cast<const float4*>(X) + ((size_t)(b * Ss + c * Sc2)) * D4 + t;
  float4 s = f4(0.f);
#pragma unroll 4
  for (int i = 0; i < Sc2; ++i) s = add4(s, xp[(size_t)i * D4]);
  st4(pp, ((size_t)b * NC + c) * D4 + t, s);
}

// fused softmax-apply + residual + LayerNorm, in place. One block per row.
// val = p*rdv*(ml ? ml : vs*x) + rs*x, p = exp(ei*fm(qs*x) - M); null scale => 1
__global__ __launch_bounds__(Tb) void k_ln(float* __restrict__ X, const float* __restrict__ qs,
    const float* __restrict__ vs, const float* __restrict__ rs, const float* __restrict__ ml,
    const float* __restrict__ ei, const float* __restrict__ Mv, const float* __restrict__ rdv,
    const float* __restrict__ g, const float* __restrict__ bt) {
  const int row = blockIdx.x;
  const int b = row >> 11;
  const int t = threadIdx.x;
  float4* xp = reinterpret_cast<float4*>(X) + (size_t)row * D4 + t;
  float4 x = *xp;
  const size_t j4 = (size_t)b * D4 + t;
  const float4 e4 = ld4(ei, j4), M4 = ld4(Mv, j4), rv4 = ld4(rdv, j4);
  const float4 q4 = qs ? ld4(qs, j4) : f4(1.f);
  float4 qf = fm4(mul4(q4, x));
  float4 p = mul4(pexp4(e4, qf, M4), rv4);
  float4 v;
  if (ml) v = mul4(p, ld4(ml, j4));
  else if (vs) v = mul4(p, mul4(ld4(vs, j4), x));
  else v = mul4(p, x);
  float4 r = rs ? mul4(ld4(rs, j4), x) : x;
  float4 val = add4(v, r);
  float sum = val.x + val.y + val.z + val.w;
  sum = blockSum(sum);
  const float mu = sum * (1.0f / Dd);
  float vv = 0.f;
  { float d0 = val.x - mu, d1 = val.y - mu, d2 = val.z - mu, d3 = val.w - mu;
    vv = d0 * d0 + d1 * d1 + d2 * d2 + d3 * d3; }
  vv = blockSum(vv);
  const float inv = rsqrtf(vv * (1.0f / Dd) + 1e-5f);
  const float4 g4 = ld4(g, t), b4 = ld4(bt, t);
  float4 y;
  y.x = fmaf((val.x - mu) * inv, g4.x, b4.x);
  y.y = fmaf((val.y - mu) * inv, g4.y, b4.y);
  y.z = fmaf((val.z - mu) * inv, g4.z, b4.z);
  y.w = fmaf((val.w - mu) * inv, g4.w, b4.w);
  *xp = y;
}

// ---------- tiny reducers: grid(32), 256 thr, thread = scalar column j=(b,d) ----------

// exclusive prefix of cs over chunks -> off; e = sum(el + off*cs); last = column total
__global__ __launch_bounds__(Tb) void t_scan(const float* __restrict__ cs, const float* __restrict__ el,
    float* __restrict__ off, float* __restrict__ eout, float* __restrict__ last) {
  const int j = blockIdx.x * Tb + threadIdx.x;
  const int b = j >> 10, d = j & 1023;
  float o = 0.f, e = 0.f;
  for (int c = 0; c < NC; ++c) {
    const size_t idx = ((size_t)(b * NC + c)) * Dd + d;
    float s = cs[idx], l = el[idx];
    off[idx] = o;
    e += l + o * s;
    o += s;
  }
  eout[j] = e;
  if (last) last[j] = o;
}

// reduce p1 partials -> ei = ec/scale, M = ei * (ec>=0 ? mx : mn)
__global__ __launch_bounds__(Tb) void t_m(const float* __restrict__ pe, const float* __restrict__ pmn,
    const float* __restrict__ pmx, float* __restrict__ ei, float* __restrict__ Mv) {
  const int j = blockIdx.x * Tb + threadIdx.x;
  const int b = j >> 10, d = j & 1023;
  float ec = 0.f, mn = BIG, mx = 0.f;
  for (int c = 0; c < NC; ++c) {
    const size_t idx = ((size_t)(b * NC + c)) * Dd + d;
    ec += pe[idx];
    mn = fminf(mn, pmn[idx]);
    mx = fmaxf(mx, pmx[idx]);
  }
  const float e2 = ec * INV_SCALE;
  ei[j] = e2;
  Mv[j] = (ec >= 0.f) ? e2 * mx : e2 * mn;
}

// reduce cross p1 partials, combine with k2 -> ei, M
__global__ __launch_bounds__(Tb) void t_xm(const float* __restrict__ pe, const float* __restrict__ pmn,
    const float* __restrict__ pmx, const float* __restrict__ k2, float* __restrict__ ei, float* __restrict__ Mv) {
  const int j = blockIdx.x * Tb + threadIdx.x;
  const int b = j >> 10, d = j & 1023;
  float cq = 0.f, mn = BIG, mx = 0.f;
  for (int c = 0; c < NC; ++c) {
    const size_t idx = ((size_t)(b * NC + c)) * Dd + d;
    cq += pe[idx];
    mn = fminf(mn, pmn[idx]);
    mx = fmaxf(mx, pmx[idx]);
  }
  const float ec = fm_act(k2[j]) * cq;
  const float e2 = ec * INV_SCALE;
  ei[j] = e2;
  Mv[j] = (ec >= 0.f) ? e2 * mx : e2 * mn;
}

// reduce sumexp partials -> reciprocal
__global__ __launch_bounds__(Tb) void t_r(const float* __restrict__ ps, float* __restrict__ rdv) {
  const int j = blockIdx.x * Tb + threadIdx.x;
  const int b = j >> 10, d = j & 1023;
  float s = 0.f;
  for (int c = 0; c < NC; ++c) s += ps[((size_t)(b * NC + c)) * Dd + d];
  rdv[j] = 1.0f / s;
}

// reduce column partials -> vector
__global__ __launch_bounds__(Tb) void t_red(const float* __restrict__ pp, float* __restrict__ outv) {
  const int j = blockIdx.x * Tb + threadIdx.x;
  const int b = j >> 10, d = j & 1023;
  float s = 0.f;
  for (int c = 0; c < NC; ++c) s += pp[((size_t)(b * NC + c)) * Dd + d];
  outv[j] = s;
}

// out[b,o] = (pooled[b,:]/S) @ Wc + bc
__global__ __launch_bounds__(Tb) void k_final(const float* __restrict__ pooled, const float* __restrict__ Wc,
    const float* __restrict__ bc, float* __restrict__ out) {
  const int b = blockIdx.x, t = threadIdx.x;
  float4 acc = ld4(pooled, (size_t)b * D4 + t);
  float4 w0 = ld4(Wc, 2 * t), w1 = ld4(Wc, 2 * t + 1);
  float s0 = acc.x * w0.x + acc.y * w0.z + acc.z * w1.x + acc.w * w1.z;
  float s1 = acc.x * w0.y + acc.y * w0.w + acc.z * w1.y + acc.w * w1.w;
  s0 = blockSum(s0);
  s1 = blockSum(s1);
  if (t == 0) {
    out[b * 2 + 0] = s0 * (1.0f / Ss) + bc[0];
    out[b * 2 + 1] = s1 * (1.0f / Ss) + bc[1];
  }
}

}  // namespace

extern "C" void kernel_launch(void* const* d_in, const int* in_sizes, int n_in,
                              void* d_out, int out_size, void* d_ws, size_t ws_size,
                              hipStream_t stream) {
  (void)in_sizes; (void)n_in; (void)out_size; (void)ws_size;
  const int* src = (const int*)d_in[0];
  const int* trg = (const int*)d_in[1];
  const float* emb = (const float*)d_in[2];
  const float* enc_g = (const float*)d_in[3];
  const float* enc_b = (const float*)d_in[4];
  const float* dec_ng = (const float*)d_in[5];
  const float* dec_nb = (const float*)d_in[6];
  const float* dec_tg = (const float*)d_in[7];
  const float* dec_tb = (const float*)d_in[8];
  const float* Wc = (const float*)d_in[9];
  const float* bc = (const float*)d_in[10];
  float* out = (float*)d_out;

  float* ws = (float*)d_ws;
  const size_t TEN = (size_t)Bb * Ss * Dd;      // 16M floats
  const size_t MM = (size_t)Bb * NC * Dd;       // 1M floats
  float* A0 = ws;
  float* cs = A0 + TEN;
  float* el = cs + MM;
  float* off = el + MM;
  float* pe = off + MM;
  float* pmn = pe + MM;
  float* pmx = pmn + MM;
  float* ps = pmx + MM;
  float* sv = ps + MM;
  const int BD = Bb * Dd;
  auto SV = [&](int i) { return sv + (size_t)i * BD; };
  // 0:e0 1:e1 2:e0d 3:e1d 4:ei 5:Mv 6:rdv 7:enc_ctx 8:v2 9:pooled

  const dim3 gC(NC, Bb);
  const int LNG = Bb * Ss;

  // ================= encoder =================
  k_gather_cs<<<gC, Tb, 0, stream>>>(src, emb, A0, cs, el);
  t_scan<<<32, Tb, 0, stream>>>(cs, el, off, SV(0), nullptr);
  k_p1<<<gC, Tb, 0, stream>>>(A0, SV(0), off, pe, pmn, pmx);
  t_m<<<32, Tb, 0, stream>>>(pe, pmn, pmx, SV(4), SV(5));
  k_p2<<<gC, Tb, 0, stream>>>(A0, SV(0), SV(4), SV(5), ps);
  t_r<<<32, Tb, 0, stream>>>(ps, SV(6));
  k_ln<<<LNG, Tb, 0, stream>>>(A0, SV(0), SV(0), SV(0), nullptr, SV(4), SV(5), SV(6), enc_g, enc_b);
  k_cs<<<gC, Tb, 0, stream>>>(A0, cs, el);
  t_scan<<<32, Tb, 0, stream>>>(cs, el, off, SV(1), SV(7));       // enc_ctx = last
  k_p1<<<gC, Tb, 0, stream>>>(A0, nullptr, off, pe, pmn, pmx);
  t_m<<<32, Tb, 0, stream>>>(pe, pmn, pmx, SV(4), SV(5));
  k_p2<<<gC, Tb, 0, stream>>>(A0, nullptr, SV(4), SV(5), ps);
  t_r<<<32, Tb, 0, stream>>>(ps, SV(6));
  k_ln<<<LNG, Tb, 0, stream>>>(A0, nullptr, SV(1), nullptr, nullptr, SV(4), SV(5), SV(6), enc_g + Dd, enc_b + Dd);
  k_colp<<<gC, Tb, 0, stream>>>(A0, pe);
  t_red<<<32, Tb, 0, stream>>>(pe, SV(8));                        // v2

  // ================= decoder =================
  k_gather_cs<<<gC, Tb, 0, stream>>>(trg, emb, A0, cs, el);
  t_scan<<<32, Tb, 0, stream>>>(cs, el, off, SV(2), nullptr);
  k_p1<<<gC, Tb, 0, stream>>>(A0, SV(2), off, pe, pmn, pmx);
  t_m<<<32, Tb, 0, stream>>>(pe, pmn, pmx, SV(4), SV(5));
  k_p2<<<gC, Tb, 0, stream>>>(A0, SV(2), SV(4), SV(5), ps);
  t_r<<<32, Tb, 0, stream>>>(ps, SV(6));
  k_ln<<<LNG, Tb, 0, stream>>>(A0, SV(2), SV(2), SV(2), nullptr, SV(4), SV(5), SV(6), dec_ng, dec_nb);
  k_xp1<<<gC, Tb, 0, stream>>>(A0, pe, pmn, pmx);
  t_xm<<<32, Tb, 0, stream>>>(pe, pmn, pmx, SV(7), SV(4), SV(5));
  k_p2<<<gC, Tb, 0, stream>>>(A0, nullptr, SV(4), SV(5), ps);
  t_r<<<32, Tb, 0, stream>>>(ps, SV(6));
  k_ln<<<LNG, Tb, 0, stream>>>(A0, nullptr, nullptr, nullptr, SV(8), SV(4), SV(5), SV(6), dec_tg, dec_tb);
  k_cs<<<gC, Tb, 0, stream>>>(A0, cs, el);
  t_scan<<<32, Tb, 0, stream>>>(cs, el, off, SV(3), nullptr);
  k_p1<<<gC, Tb, 0, stream>>>(A0, nullptr, off, pe, pmn, pmx);
  t_m<<<32, Tb, 0, stream>>>(pe, pmn, pmx, SV(4), SV(5));
  k_p2<<<gC, Tb, 0, stream>>>(A0, nullptr, SV(4), SV(5), ps);
  t_r<<<32, Tb, 0, stream>>>(ps, SV(6));
  k_ln<<<LNG, Tb, 0, stream>>>(A0, nullptr, SV(3), nullptr, nullptr, SV(4), SV(5), SV(6), dec_ng + Dd, dec_nb + Dd);
  k_xp1<<<gC, Tb, 0, stream>>>(A0, pe, pmn, pmx);
  t_xm<<<32, Tb, 0, stream>>>(pe, pmn, pmx, SV(7), SV(4), SV(5));
  k_p2<<<gC, Tb, 0, stream>>>(A0, nullptr, SV(4), SV(5), ps);
  t_r<<<32, Tb, 0, stream>>>(ps, SV(6));
  k_ln<<<LNG, Tb, 0, stream>>>(A0, nullptr, nullptr, nullptr, SV(8), SV(4), SV(5), SV(6), dec_tg + Dd, dec_tb + Dd);
  k_colp<<<gC, Tb, 0, stream>>>(A0, pe);
  t_red<<<32, Tb, 0, stream>>>(pe, SV(9));                        // pooled (unnormalized)
  k_final<<<Bb, Tb, 0, stream>>>(SV(9), Wc, bc, out);
}

// Round 3
// 644.201 us; speedup vs baseline: 1.8609x; 1.1095x over previous
//
#include <hip/hip_runtime.h>
#include <math.h>

namespace {

constexpr int Bb = 8;
constexpr int Ss = 2048;
constexpr int Dd = 1024;
constexpr int D4 = Dd / 4;        // float4 per row
constexpr int NC = 256;           // s-chunks
constexpr int Sc2 = Ss / NC;      // 8 rows per chunk
constexpr int Tb = 256;
constexpr int SEG = 8;            // segments per column in tiny reducers
constexpr int CPS = NC / SEG;     // 32 chunks per segment
constexpr float INV_SCALE = 0.03125f;  // 1/sqrt(1024)
constexpr float BIG = 3.0e38f;

// gelu(x, exact) + 1
__device__ __forceinline__ float fm_act(float x) {
  return fmaf(0.5f * x, 1.0f + erff(x * 0.70710678118654752f), 1.0f);
}

__device__ __forceinline__ float4 f4(float v) { return make_float4(v, v, v, v); }
__device__ __forceinline__ float4 add4(float4 a, float4 b) {
  return make_float4(a.x + b.x, a.y + b.y, a.z + b.z, a.w + b.w);
}
__device__ __forceinline__ float4 mul4(float4 a, float4 b) {
  return make_float4(a.x * b.x, a.y * b.y, a.z * b.z, a.w * b.w);
}
__device__ __forceinline__ float4 fma4(float4 a, float4 b, float4 c) {
  return make_float4(fmaf(a.x, b.x, c.x), fmaf(a.y, b.y, c.y), fmaf(a.z, b.z, c.z), fmaf(a.w, b.w, c.w));
}
__device__ __forceinline__ float4 min4(float4 a, float4 b) {
  return make_float4(fminf(a.x, b.x), fminf(a.y, b.y), fminf(a.z, b.z), fminf(a.w, b.w));
}
__device__ __forceinline__ float4 max4(float4 a, float4 b) {
  return make_float4(fmaxf(a.x, b.x), fmaxf(a.y, b.y), fmaxf(a.z, b.z), fmaxf(a.w, b.w));
}
__device__ __forceinline__ float4 fm4(float4 x) {
  return make_float4(fm_act(x.x), fm_act(x.y), fm_act(x.z), fm_act(x.w));
}
__device__ __forceinline__ float4 ld4(const float* p, size_t j4) {
  return reinterpret_cast<const float4*>(p)[j4];
}
__device__ __forceinline__ void st4(float* p, size_t j4, float4 v) {
  reinterpret_cast<float4*>(p)[j4] = v;
}
__device__ __forceinline__ float4 pexp4(float4 ei, float4 qf, float4 M) {
  return make_float4(expf(fmaf(ei.x, qf.x, -M.x)), expf(fmaf(ei.y, qf.y, -M.y)),
                     expf(fmaf(ei.z, qf.z, -M.z)), expf(fmaf(ei.w, qf.w, -M.w)));
}

__device__ __forceinline__ float blockSum(float v) {
  __shared__ float wsm[Tb / 64];
  for (int off = 32; off > 0; off >>= 1) v += __shfl_down(v, off, 64);
  const int lane = threadIdx.x & 63;
  const int w = threadIdx.x >> 6;
  __syncthreads();
  if (lane == 0) wsm[w] = v;
  __syncthreads();
  return wsm[0] + wsm[1] + wsm[2] + wsm[3];
}

// ---------- big column-pass kernels: grid(NC, B), 256 thr, thread t = float4 at d=4t ----------

__global__ __launch_bounds__(Tb) void k_gather_cs(const int* __restrict__ tok, const float* __restrict__ emb,
    float* __restrict__ X, float* __restrict__ cs, float* __restrict__ el) {
  const int t = threadIdx.x, c = blockIdx.x, b = blockIdx.y;
  const int* tp = tok + b * Ss + c * Sc2;
  float4* xp = reinterpret_cast<float4*>(X) + ((size_t)(b * Ss + c * Sc2)) * D4 + t;
  const float4* ep = reinterpret_cast<const float4*>(emb);
  float4 run = f4(0.f), e = f4(0.f);
#pragma unroll
  for (int i = 0; i < Sc2; ++i) {
    float4 v = ep[(size_t)tp[i] * D4 + t];
    xp[(size_t)i * D4] = v;
    run = add4(run, v);
    e = fma4(v, run, e);
  }
  const size_t idx = ((size_t)b * NC + c) * D4 + t;
  st4(cs, idx, run);
  st4(el, idx, e);
}

// self-attn p1: ctx from off + running sum; partial ecol & qf min/max per chunk
__global__ __launch_bounds__(Tb) void k_p1(const float* __restrict__ X, const float* __restrict__ qs,
    const float* __restrict__ off, float* __restrict__ pe, float* __restrict__ pmn, float* __restrict__ pmx) {
  const int t = threadIdx.x, c = blockIdx.x, b = blockIdx.y;
  const size_t idx = ((size_t)b * NC + c) * D4 + t;
  float4 run = ld4(off, idx);
  const float4 q4 = qs ? ld4(qs, (size_t)b * D4 + t) : f4(1.f);
  const float4* xp = reinterpret_cast<const float4*>(X) + ((size_t)(b * Ss + c * Sc2)) * D4 + t;
  float4 e = f4(0.f), mn = f4(BIG), mx = f4(0.f);
#pragma unroll
  for (int i = 0; i < Sc2; ++i) {
    float4 x = xp[(size_t)i * D4];
    run = add4(run, x);
    float4 qf = fm4(mul4(q4, x));
    float4 kf = fm4(run);
    e = fma4(qf, kf, e);
    mn = min4(mn, qf);
    mx = max4(mx, qf);
  }
  st4(pe, idx, e);
  st4(pmn, idx, mn);
  st4(pmx, idx, mx);
}

// p2: partial sumexp per chunk (self [qs] and cross [qs=null])
__global__ __launch_bounds__(Tb) void k_p2(const float* __restrict__ X, const float* __restrict__ qs,
    const float* __restrict__ ei, const float* __restrict__ Mv, float* __restrict__ ps) {
  const int t = threadIdx.x, c = blockIdx.x, b = blockIdx.y;
  const size_t j4 = (size_t)b * D4 + t;
  const float4 q4 = qs ? ld4(qs, j4) : f4(1.f);
  const float4 e4 = ld4(ei, j4);
  const float4 M4 = ld4(Mv, j4);
  const float4* xp = reinterpret_cast<const float4*>(X) + ((size_t)(b * Ss + c * Sc2)) * D4 + t;
  float4 s = f4(0.f);
#pragma unroll
  for (int i = 0; i < Sc2; ++i) {
    float4 x = xp[(size_t)i * D4];
    float4 qf = fm4(mul4(q4, x));
    s = add4(s, pexp4(e4, qf, M4));
  }
  st4(ps, ((size_t)b * NC + c) * D4 + t, s);
}

// cross-attn p1: partial colsum(fm(x)) + min/max
__global__ __launch_bounds__(Tb) void k_xp1(const float* __restrict__ X, float* __restrict__ pe,
    float* __restrict__ pmn, float* __restrict__ pmx) {
  const int t = threadIdx.x, c = blockIdx.x, b = blockIdx.y;
  const float4* xp = reinterpret_cast<const float4*>(X) + ((size_t)(b * Ss + c * Sc2)) * D4 + t;
  float4 s = f4(0.f), mn = f4(BIG), mx = f4(0.f);
#pragma unroll
  for (int i = 0; i < Sc2; ++i) {
    float4 qf = fm4(xp[(size_t)i * D4]);
    s = add4(s, qf);
    mn = min4(mn, qf);
    mx = max4(mx, qf);
  }
  const size_t idx = ((size_t)b * NC + c) * D4 + t;
  st4(pe, idx, s);
  st4(pmn, idx, mn);
  st4(pmx, idx, mx);
}

// fused softmax-apply + residual + LayerNorm (in place) + chunk column sums & gds partials.
// block = chunk of Sc2 rows. val = p*rdv*(ml ? ml : vs*x) + rs*x, p = exp(ei*fm(qs*x) - M)
__global__ __launch_bounds__(Tb) void k_ln_cs(float* __restrict__ X, const float* __restrict__ qs,
    const float* __restrict__ vs, const float* __restrict__ rs, const float* __restrict__ ml,
    const float* __restrict__ ei, const float* __restrict__ Mv, const float* __restrict__ rdv,
    const float* __restrict__ g, const float* __restrict__ bt,
    float* __restrict__ cs, float* __restrict__ el) {
  __shared__ float red[Sc2][Tb];
  __shared__ float mu_s[Sc2], inv_s[Sc2];
  const int t = threadIdx.x, c = blockIdx.x, b = blockIdx.y;
  float4* xp = reinterpret_cast<float4*>(X) + ((size_t)(b * Ss + c * Sc2)) * D4 + t;
  const size_t j4 = (size_t)b * D4 + t;
  const float4 e4 = ld4(ei, j4), M4 = ld4(Mv, j4), rv4 = ld4(rdv, j4);
  const float4 q4 = qs ? ld4(qs, j4) : f4(1.f);
  const float4 vs4 = vs ? ld4(vs, j4) : f4(1.f);
  const float4 ml4 = ml ? ld4(ml, j4) : f4(1.f);
  const float4 rs4 = rs ? ld4(rs, j4) : f4(1.f);
  float4 vals[Sc2];
#pragma unroll
  for (int i = 0; i < Sc2; ++i) {
    float4 x = xp[(size_t)i * D4];
    float4 qf = fm4(mul4(q4, x));
    float4 p = mul4(pexp4(e4, qf, M4), rv4);
    float4 v = ml ? mul4(p, ml4) : mul4(p, mul4(vs4, x));
    float4 val = add4(v, mul4(rs4, x));
    vals[i] = val;
    red[i][t] = val.x + val.y + val.z + val.w;
  }
  __syncthreads();
  const int lane = t & 63, w = t >> 6;
#pragma unroll
  for (int rr = 0; rr < Sc2 / 4; ++rr) {
    const int row = w * (Sc2 / 4) + rr;
    float s = red[row][lane] + red[row][lane + 64] + red[row][lane + 128] + red[row][lane + 192];
    for (int off = 32; off > 0; off >>= 1) s += __shfl_down(s, off, 64);
    if (lane == 0) mu_s[row] = s * (1.0f / Dd);
  }
  __syncthreads();
#pragma unroll
  for (int i = 0; i < Sc2; ++i) {
    const float m = mu_s[i];
    float4 vv = vals[i];
    float a = vv.x - m, b2 = vv.y - m, c2 = vv.z - m, d2 = vv.w - m;
    red[i][t] = a * a + b2 * b2 + c2 * c2 + d2 * d2;
  }
  __syncthreads();
#pragma unroll
  for (int rr = 0; rr < Sc2 / 4; ++rr) {
    const int row = w * (Sc2 / 4) + rr;
    float s = red[row][lane] + red[row][lane + 64] + red[row][lane + 128] + red[row][lane + 192];
    for (int off = 32; off > 0; off >>= 1) s += __shfl_down(s, off, 64);
    if (lane == 0) inv_s[row] = rsqrtf(s * (1.0f / Dd) + 1e-5f);
  }
  __syncthreads();
  const float4 g4 = ld4(g, t), b4 = ld4(bt, t);
  float4 run = f4(0.f), e = f4(0.f);
#pragma unroll
  for (int i = 0; i < Sc2; ++i) {
    const float m = mu_s[i], inv = inv_s[i];
    float4 vv = vals[i];
    float4 y;
    y.x = fmaf((vv.x - m) * inv, g4.x, b4.x);
    y.y = fmaf((vv.y - m) * inv, g4.y, b4.y);
    y.z = fmaf((vv.z - m) * inv, g4.z, b4.z);
    y.w = fmaf((vv.w - m) * inv, g4.w, b4.w);
    xp[(size_t)i * D4] = y;
    run = add4(run, y);
    e = fma4(y, run, e);
  }
  const size_t idx = ((size_t)b * NC + c) * D4 + t;
  st4(cs, idx, run);
  st4(el, idx, e);
}

// ---------- tiny reducers: grid(BD/32), 256 thr = 32 columns x 8 segments ----------

// segmented exclusive prefix of cs over chunks -> off; e = sum(el + off*cs); last = column total
__global__ __launch_bounds__(Tb) void t_scan8(const float* __restrict__ cs, const float* __restrict__ el,
    float* __restrict__ off, float* __restrict__ eout, float* __restrict__ last) {
  __shared__ float lds[SEG][32];
  const int tid = threadIdx.x;
  const int jl = tid & 31, seg = tid >> 5;
  const int j = blockIdx.x * 32 + jl;
  const int b = j >> 10, d = j & 1023;
  const size_t base = (size_t)b * NC * Dd + d;
  float s = 0.f;
#pragma unroll 8
  for (int i = 0; i < CPS; ++i) s += cs[base + (size_t)(seg * CPS + i) * Dd];
  lds[seg][jl] = s;
  __syncthreads();
  float o = 0.f;
#pragma unroll
  for (int g2 = 0; g2 < SEG; ++g2) { float v = lds[g2][jl]; o += (g2 < seg) ? v : 0.f; }
  __syncthreads();
  float run = o, e = 0.f;
#pragma unroll 8
  for (int i = 0; i < CPS; ++i) {
    const size_t k = base + (size_t)(seg * CPS + i) * Dd;
    float cv = cs[k];
    off[k] = run;
    e += el[k] + run * cv;
    run += cv;
  }
  lds[seg][jl] = e;
  __syncthreads();
  if (seg == 0) {
    float et = 0.f;
#pragma unroll
    for (int g2 = 0; g2 < SEG; ++g2) et += lds[g2][jl];
    eout[j] = et;
  }
  if (last && seg == SEG - 1) last[j] = run;
}

// reduce p1 partials -> ei, Mv. k2 non-null => cross (ec = fm(k2)*colsum)
__global__ __launch_bounds__(Tb) void t_m8(const float* __restrict__ pe, const float* __restrict__ pmn,
    const float* __restrict__ pmx, const float* __restrict__ k2, float* __restrict__ ei, float* __restrict__ Mv) {
  __shared__ float le[SEG][32], lmn[SEG][32], lmx[SEG][32];
  const int tid = threadIdx.x;
  const int jl = tid & 31, seg = tid >> 5;
  const int j = blockIdx.x * 32 + jl;
  const int b = j >> 10, d = j & 1023;
  const size_t base = (size_t)b * NC * Dd + d;
  float ec = 0.f, mn = BIG, mx = 0.f;
#pragma unroll 8
  for (int i = 0; i < CPS; ++i) {
    const size_t k = base + (size_t)(seg * CPS + i) * Dd;
    ec += pe[k];
    mn = fminf(mn, pmn[k]);
    mx = fmaxf(mx, pmx[k]);
  }
  le[seg][jl] = ec; lmn[seg][jl] = mn; lmx[seg][jl] = mx;
  __syncthreads();
  if (seg == 0) {
#pragma unroll
    for (int g2 = 1; g2 < SEG; ++g2) {
      ec += le[g2][jl];
      mn = fminf(mn, lmn[g2][jl]);
      mx = fmaxf(mx, lmx[g2][jl]);
    }
    if (k2) ec *= fm_act(k2[j]);
    const float e2 = ec * INV_SCALE;
    ei[j] = e2;
    Mv[j] = (ec >= 0.f) ? e2 * mx : e2 * mn;
  }
}

// reduce partials -> sum (recip=0) or 1/sum (recip=1)
__global__ __launch_bounds__(Tb) void t_red8(const float* __restrict__ pp, float* __restrict__ outv, int recip) {
  __shared__ float lds[SEG][32];
  const int tid = threadIdx.x;
  const int jl = tid & 31, seg = tid >> 5;
  const int j = blockIdx.x * 32 + jl;
  const int b = j >> 10, d = j & 1023;
  const size_t base = (size_t)b * NC * Dd + d;
  float s = 0.f;
#pragma unroll 8
  for (int i = 0; i < CPS; ++i) s += pp[base + (size_t)(seg * CPS + i) * Dd];
  lds[seg][jl] = s;
  __syncthreads();
  if (seg == 0) {
#pragma unroll
    for (int g2 = 1; g2 < SEG; ++g2) s += lds[g2][jl];
    outv[j] = recip ? 1.0f / s : s;
  }
}

// out[b,o] = (pooled[b,:]/S) @ Wc + bc
__global__ __launch_bounds__(Tb) void k_final(const float* __restrict__ pooled, const float* __restrict__ Wc,
    const float* __restrict__ bc, float* __restrict__ out) {
  const int b = blockIdx.x, t = threadIdx.x;
  float4 acc = ld4(pooled, (size_t)b * D4 + t);
  float4 w0 = ld4(Wc, 2 * t), w1 = ld4(Wc, 2 * t + 1);
  float s0 = acc.x * w0.x + acc.y * w0.z + acc.z * w1.x + acc.w * w1.z;
  float s1 = acc.x * w0.y + acc.y * w0.w + acc.z * w1.y + acc.w * w1.w;
  s0 = blockSum(s0);
  s1 = blockSum(s1);
  if (t == 0) {
    out[b * 2 + 0] = s0 * (1.0f / Ss) + bc[0];
    out[b * 2 + 1] = s1 * (1.0f / Ss) + bc[1];
  }
}

}  // namespace

extern "C" void kernel_launch(void* const* d_in, const int* in_sizes, int n_in,
                              void* d_out, int out_size, void* d_ws, size_t ws_size,
                              hipStream_t stream) {
  (void)in_sizes; (void)n_in; (void)out_size; (void)ws_size;
  const int* src = (const int*)d_in[0];
  const int* trg = (const int*)d_in[1];
  const float* emb = (const float*)d_in[2];
  const float* enc_g = (const float*)d_in[3];
  const float* enc_b = (const float*)d_in[4];
  const float* dec_ng = (const float*)d_in[5];
  const float* dec_nb = (const float*)d_in[6];
  const float* dec_tg = (const float*)d_in[7];
  const float* dec_tb = (const float*)d_in[8];
  const float* Wc = (const float*)d_in[9];
  const float* bc = (const float*)d_in[10];
  float* out = (float*)d_out;

  float* ws = (float*)d_ws;
  const size_t TEN = (size_t)Bb * Ss * Dd;      // 16M floats
  const size_t MM = (size_t)Bb * NC * Dd;       // 2M floats
  float* A0 = ws;
  float* cs = A0 + TEN;
  float* el = cs + MM;
  float* off = el + MM;
  float* pe = off + MM;
  float* pmn = pe + MM;
  float* pmx = pmn + MM;
  float* ps = pmx + MM;
  float* sv = ps + MM;
  const int BD = Bb * Dd;
  auto SV = [&](int i) { return sv + (size_t)i * BD; };
  // 0:e0 1:e1 2:e0d 3:e1d 4:ei 5:Mv 6:rdv 7:enc_ctx 8:v2 9:pooled

  const dim3 gC(NC, Bb);
  const int TG = BD / 32;   // 256 blocks for tiny reducers

  // ================= encoder =================
  k_gather_cs<<<gC, Tb, 0, stream>>>(src, emb, A0, cs, el);
  t_scan8<<<TG, Tb, 0, stream>>>(cs, el, off, SV(0), nullptr);
  k_p1<<<gC, Tb, 0, stream>>>(A0, SV(0), off, pe, pmn, pmx);
  t_m8<<<TG, Tb, 0, stream>>>(pe, pmn, pmx, nullptr, SV(4), SV(5));
  k_p2<<<gC, Tb, 0, stream>>>(A0, SV(0), SV(4), SV(5), ps);
  t_red8<<<TG, Tb, 0, stream>>>(ps, SV(6), 1);
  k_ln_cs<<<gC, Tb, 0, stream>>>(A0, SV(0), SV(0), SV(0), nullptr, SV(4), SV(5), SV(6), enc_g, enc_b, cs, el);
  t_scan8<<<TG, Tb, 0, stream>>>(cs, el, off, SV(1), SV(7));              // enc_ctx = last
  k_p1<<<gC, Tb, 0, stream>>>(A0, nullptr, off, pe, pmn, pmx);
  t_m8<<<TG, Tb, 0, stream>>>(pe, pmn, pmx, nullptr, SV(4), SV(5));
  k_p2<<<gC, Tb, 0, stream>>>(A0, nullptr, SV(4), SV(5), ps);
  t_red8<<<TG, Tb, 0, stream>>>(ps, SV(6), 1);
  k_ln_cs<<<gC, Tb, 0, stream>>>(A0, nullptr, SV(1), nullptr, nullptr, SV(4), SV(5), SV(6), enc_g + Dd, enc_b + Dd, cs, el);
  t_red8<<<TG, Tb, 0, stream>>>(cs, SV(8), 0);                            // v2

  // ================= decoder =================
  k_gather_cs<<<gC, Tb, 0, stream>>>(trg, emb, A0, cs, el);
  t_scan8<<<TG, Tb, 0, stream>>>(cs, el, off, SV(2), nullptr);
  k_p1<<<gC, Tb, 0, stream>>>(A0, SV(2), off, pe, pmn, pmx);
  t_m8<<<TG, Tb, 0, stream>>>(pe, pmn, pmx, nullptr, SV(4), SV(5));
  k_p2<<<gC, Tb, 0, stream>>>(A0, SV(2), SV(4), SV(5), ps);
  t_red8<<<TG, Tb, 0, stream>>>(ps, SV(6), 1);
  k_ln_cs<<<gC, Tb, 0, stream>>>(A0, SV(2), SV(2), SV(2), nullptr, SV(4), SV(5), SV(6), dec_ng, dec_nb, cs, el);
  k_xp1<<<gC, Tb, 0, stream>>>(A0, pe, pmn, pmx);
  t_m8<<<TG, Tb, 0, stream>>>(pe, pmn, pmx, SV(7), SV(4), SV(5));
  k_p2<<<gC, Tb, 0, stream>>>(A0, nullptr, SV(4), SV(5), ps);
  t_red8<<<TG, Tb, 0, stream>>>(ps, SV(6), 1);
  k_ln_cs<<<gC, Tb, 0, stream>>>(A0, nullptr, nullptr, nullptr, SV(8), SV(4), SV(5), SV(6), dec_tg, dec_tb, cs, el);
  t_scan8<<<TG, Tb, 0, stream>>>(cs, el, off, SV(3), nullptr);
  k_p1<<<gC, Tb, 0, stream>>>(A0, nullptr, off, pe, pmn, pmx);
  t_m8<<<TG, Tb, 0, stream>>>(pe, pmn, pmx, nullptr, SV(4), SV(5));
  k_p2<<<gC, Tb, 0, stream>>>(A0, nullptr, SV(4), SV(5), ps);
  t_red8<<<TG, Tb, 0, stream>>>(ps, SV(6), 1);
  k_ln_cs<<<gC, Tb, 0, stream>>>(A0, nullptr, SV(3), nullptr, nullptr, SV(4), SV(5), SV(6), dec_ng + Dd, dec_nb + Dd, cs, el);
  k_xp1<<<gC, Tb, 0, stream>>>(A0, pe, pmn, pmx);
  t_m8<<<TG, Tb, 0, stream>>>(pe, pmn, pmx, SV(7), SV(4), SV(5));
  k_p2<<<gC, Tb, 0, stream>>>(A0, nullptr, SV(4), SV(5), ps);
  t_red8<<<TG, Tb, 0, stream>>>(ps, SV(6), 1);
  k_ln_cs<<<gC, Tb, 0, stream>>>(A0, nullptr, nullptr, nullptr, SV(8), SV(4), SV(5), SV(6), dec_tg + Dd, dec_tb + Dd, cs, el);
  t_red8<<<TG, Tb, 0, stream>>>(cs, SV(9), 0);                            // pooled (unnormalized)
  k_final<<<Bb, Tb, 0, stream>>>(SV(9), Wc, bc, out);
}

// Round 5
// 476.448 us; speedup vs baseline: 2.5161x; 1.3521x over previous
//
#include <hip/hip_runtime.h>
#include <math.h>

namespace {

constexpr int Bb = 8;
constexpr int Ss = 2048;
constexpr int Dd = 1024;
constexpr int D4 = Dd / 4;        // float4 per row
constexpr int NC = 256;           // s-chunks
constexpr int Sc2 = Ss / NC;      // 8 rows per chunk
constexpr int Tb = 256;
constexpr int SEG = 8;            // segments per column in tiny reducers
constexpr int CPS = NC / SEG;     // 32 chunks per segment
constexpr float INV_SCALE = 0.03125f;  // 1/sqrt(1024)
constexpr float BIG = 3.0e38f;

// branch-free erf, Abramowitz-Stegun 7.1.26, |abs err| <= 1.5e-7
__device__ __forceinline__ float fast_erf(float z) {
  float az = fabsf(z);
  float t = __builtin_amdgcn_rcpf(fmaf(0.3275911f, az, 1.0f));
  float p = fmaf(1.061405429f, t, -1.453152027f);
  p = fmaf(p, t, 1.421413741f);
  p = fmaf(p, t, -0.284496736f);
  p = fmaf(p, t, 0.254829592f);
  p *= t;
  float e = __expf(-az * az);
  float r = fmaf(-p, e, 1.0f);
  return copysignf(r, z);
}
// gelu(x, exact) + 1
__device__ __forceinline__ float fm_act(float x) {
  return fmaf(0.5f * x, 1.0f + fast_erf(x * 0.70710678118654752f), 1.0f);
}

__device__ __forceinline__ float4 f4(float v) { return make_float4(v, v, v, v); }
__device__ __forceinline__ float4 add4(float4 a, float4 b) {
  return make_float4(a.x + b.x, a.y + b.y, a.z + b.z, a.w + b.w);
}
__device__ __forceinline__ float4 mul4(float4 a, float4 b) {
  return make_float4(a.x * b.x, a.y * b.y, a.z * b.z, a.w * b.w);
}
__device__ __forceinline__ float4 fma4(float4 a, float4 b, float4 c) {
  return make_float4(fmaf(a.x, b.x, c.x), fmaf(a.y, b.y, c.y), fmaf(a.z, b.z, c.z), fmaf(a.w, b.w, c.w));
}
__device__ __forceinline__ float4 min4(float4 a, float4 b) {
  return make_float4(fminf(a.x, b.x), fminf(a.y, b.y), fminf(a.z, b.z), fminf(a.w, b.w));
}
__device__ __forceinline__ float4 max4(float4 a, float4 b) {
  return make_float4(fmaxf(a.x, b.x), fmaxf(a.y, b.y), fmaxf(a.z, b.z), fmaxf(a.w, b.w));
}
__device__ __forceinline__ float4 fm4(float4 x) {
  return make_float4(fm_act(x.x), fm_act(x.y), fm_act(x.z), fm_act(x.w));
}
__device__ __forceinline__ float4 ld4(const float* p, size_t j4) {
  return reinterpret_cast<const float4*>(p)[j4];
}
__device__ __forceinline__ void st4(float* p, size_t j4, float4 v) {
  reinterpret_cast<float4*>(p)[j4] = v;
}
__device__ __forceinline__ float4 pexp4(float4 ei, float4 qf, float4 M) {
  return make_float4(__expf(fmaf(ei.x, qf.x, -M.x)), __expf(fmaf(ei.y, qf.y, -M.y)),
                     __expf(fmaf(ei.z, qf.z, -M.z)), __expf(fmaf(ei.w, qf.w, -M.w)));
}

__device__ __forceinline__ float blockSum(float v) {
  __shared__ float wsm[Tb / 64];
  for (int off = 32; off > 0; off >>= 1) v += __shfl_down(v, off, 64);
  const int lane = threadIdx.x & 63;
  const int w = threadIdx.x >> 6;
  __syncthreads();
  if (lane == 0) wsm[w] = v;
  __syncthreads();
  return wsm[0] + wsm[1] + wsm[2] + wsm[3];
}

// ---------- arg structs (z-mergeable kernels pick by blockIdx.z) ----------
struct GA { const int* tok; float* X; float* cs; float* el; };
struct SA { const float* cs; const float* el; float* off; float* e; float* last; };
struct PA { const float* X; const float* qs; const float* off; float* pe; float* pmn; float* pmx; };
struct MA { const float* pe; const float* pmn; const float* pmx; const float* k2; float* ei; float* Mv; };
struct QA { const float* X; const float* qs; const float* ei; const float* Mv; float* ps; };
struct RA { const float* pp; float* outv; int recip; };
struct LA { float* X; const float* qs; const float* vs; const float* rs; const float* ml;
            const float* ei; const float* Mv; const float* rdv; const float* g; const float* bt;
            float* cs; float* el; float* xe; float* xn; float* xx; };

// ---------- big column-pass kernels: grid(NC, B, nz), 256 thr, thread t = float4 at d=4t ----------

// gather emb rows + chunk colsums + local gds partial
__global__ __launch_bounds__(Tb) void k_gather(GA a0, GA a1, const float* __restrict__ emb) {
  const GA a = (blockIdx.z == 0) ? a0 : a1;
  const int t = threadIdx.x, c = blockIdx.x, b = blockIdx.y;
  const int* tp = a.tok + b * Ss + c * Sc2;
  float4* xp = reinterpret_cast<float4*>(a.X) + ((size_t)(b * Ss + c * Sc2)) * D4 + t;
  const float4* ep = reinterpret_cast<const float4*>(emb);
  float4 run = f4(0.f), e = f4(0.f);
#pragma unroll
  for (int i = 0; i < Sc2; ++i) {
    float4 v = ep[(size_t)tp[i] * D4 + t];
    xp[(size_t)i * D4] = v;
    run = add4(run, v);
    e = fma4(v, run, e);
  }
  const size_t idx = ((size_t)b * NC + c) * D4 + t;
  st4(a.cs, idx, run);
  st4(a.el, idx, e);
}

// self-attn p1: ctx from off + running sum; partial ecol & qf min/max per chunk
__global__ __launch_bounds__(Tb) void k_p1(PA a0, PA a1) {
  const PA a = (blockIdx.z == 0) ? a0 : a1;
  const int t = threadIdx.x, c = blockIdx.x, b = blockIdx.y;
  const size_t idx = ((size_t)b * NC + c) * D4 + t;
  float4 run = ld4(a.off, idx);
  const float4 q4 = a.qs ? ld4(a.qs, (size_t)b * D4 + t) : f4(1.f);
  const float4* xp = reinterpret_cast<const float4*>(a.X) + ((size_t)(b * Ss + c * Sc2)) * D4 + t;
  float4 e = f4(0.f), mn = f4(BIG), mx = f4(0.f);
#pragma unroll
  for (int i = 0; i < Sc2; ++i) {
    float4 x = xp[(size_t)i * D4];
    run = add4(run, x);
    float4 qf = fm4(mul4(q4, x));
    float4 kf = fm4(run);
    e = fma4(qf, kf, e);
    mn = min4(mn, qf);
    mx = max4(mx, qf);
  }
  st4(a.pe, idx, e);
  st4(a.pmn, idx, mn);
  st4(a.pmx, idx, mx);
}

// p2: partial sumexp per chunk (self [qs] and cross [qs=null])
__global__ __launch_bounds__(Tb) void k_p2(QA a0, QA a1) {
  const QA a = (blockIdx.z == 0) ? a0 : a1;
  const int t = threadIdx.x, c = blockIdx.x, b = blockIdx.y;
  const size_t j4 = (size_t)b * D4 + t;
  const float4 q4 = a.qs ? ld4(a.qs, j4) : f4(1.f);
  const float4 e4 = ld4(a.ei, j4);
  const float4 M4 = ld4(a.Mv, j4);
  const float4* xp = reinterpret_cast<const float4*>(a.X) + ((size_t)(b * Ss + c * Sc2)) * D4 + t;
  float4 s = f4(0.f);
#pragma unroll
  for (int i = 0; i < Sc2; ++i) {
    float4 x = xp[(size_t)i * D4];
    float4 qf = fm4(mul4(q4, x));
    s = add4(s, pexp4(e4, qf, M4));
  }
  st4(a.ps, ((size_t)b * NC + c) * D4 + t, s);
}

// fused softmax-apply + residual + LayerNorm (in place), optional chunk colsum/gds partials,
// optional cross-attn qf partials (colsum/min/max of fm(y)).
__global__ __launch_bounds__(Tb) void k_ln(LA a0, LA a1) {
  const LA a = (blockIdx.z == 0) ? a0 : a1;
  __shared__ float red[Sc2][Tb];
  __shared__ float mu_s[Sc2], inv_s[Sc2];
  const int t = threadIdx.x, c = blockIdx.x, b = blockIdx.y;
  float4* xp = reinterpret_cast<float4*>(a.X) + ((size_t)(b * Ss + c * Sc2)) * D4 + t;
  const size_t j4 = (size_t)b * D4 + t;
  const float4 e4 = ld4(a.ei, j4), M4 = ld4(a.Mv, j4), rv4 = ld4(a.rdv, j4);
  const float4 q4 = a.qs ? ld4(a.qs, j4) : f4(1.f);
  const float4 vs4 = a.vs ? ld4(a.vs, j4) : f4(1.f);
  const float4 ml4 = a.ml ? ld4(a.ml, j4) : f4(1.f);
  const float4 rs4 = a.rs ? ld4(a.rs, j4) : f4(1.f);
  float4 vals[Sc2];
#pragma unroll
  for (int i = 0; i < Sc2; ++i) {
    float4 x = xp[(size_t)i * D4];
    float4 qf = fm4(mul4(q4, x));
    float4 p = mul4(pexp4(e4, qf, M4), rv4);
    float4 v = a.ml ? mul4(p, ml4) : mul4(p, mul4(vs4, x));
    float4 val = add4(v, mul4(rs4, x));
    vals[i] = val;
    red[i][t] = val.x + val.y + val.z + val.w;
  }
  __syncthreads();
  const int lane = t & 63, w = t >> 6;
#pragma unroll
  for (int rr = 0; rr < Sc2 / 4; ++rr) {
    const int row = w * (Sc2 / 4) + rr;
    float s = red[row][lane] + red[row][lane + 64] + red[row][lane + 128] + red[row][lane + 192];
    for (int off = 32; off > 0; off >>= 1) s += __shfl_down(s, off, 64);
    if (lane == 0) mu_s[row] = s * (1.0f / Dd);
  }
  __syncthreads();
#pragma unroll
  for (int i = 0; i < Sc2; ++i) {
    const float m = mu_s[i];
    float4 vv = vals[i];
    float aa = vv.x - m, b2 = vv.y - m, c2 = vv.z - m, d2 = vv.w - m;
    red[i][t] = aa * aa + b2 * b2 + c2 * c2 + d2 * d2;
  }
  __syncthreads();
#pragma unroll
  for (int rr = 0; rr < Sc2 / 4; ++rr) {
    const int row = w * (Sc2 / 4) + rr;
    float s = red[row][lane] + red[row][lane + 64] + red[row][lane + 128] + red[row][lane + 192];
    for (int off = 32; off > 0; off >>= 1) s += __shfl_down(s, off, 64);
    if (lane == 0) inv_s[row] = rsqrtf(s * (1.0f / Dd) + 1e-5f);
  }
  __syncthreads();
  const float4 g4 = ld4(a.g, t), b4 = ld4(a.bt, t);
  float4 run = f4(0.f), e = f4(0.f);
  float4 xs = f4(0.f), xmn = f4(BIG), xmx = f4(0.f);
#pragma unroll
  for (int i = 0; i < Sc2; ++i) {
    const float m = mu_s[i], inv = inv_s[i];
    float4 vv = vals[i];
    float4 y;
    y.x = fmaf((vv.x - m) * inv, g4.x, b4.x);
    y.y = fmaf((vv.y - m) * inv, g4.y, b4.y);
    y.z = fmaf((vv.z - m) * inv, g4.z, b4.z);
    y.w = fmaf((vv.w - m) * inv, g4.w, b4.w);
    xp[(size_t)i * D4] = y;
    if (a.cs) {
      run = add4(run, y);
      if (a.el) e = fma4(y, run, e);
    }
    if (a.xe) {
      float4 qfy = fm4(y);
      xs = add4(xs, qfy);
      xmn = min4(xmn, qfy);
      xmx = max4(xmx, qfy);
    }
  }
  const size_t idx = ((size_t)b * NC + c) * D4 + t;
  if (a.cs) st4(a.cs, idx, run);
  if (a.el) st4(a.el, idx, e);
  if (a.xe) {
    st4(a.xe, idx, xs);
    st4(a.xn, idx, xmn);
    st4(a.xx, idx, xmx);
  }
}

// ---------- tiny reducers: grid(BD/32, 1, nz), 256 thr = 32 columns x 8 segments ----------

__global__ __launch_bounds__(Tb) void t_scan8(SA a0, SA a1) {
  const SA a = (blockIdx.z == 0) ? a0 : a1;
  __shared__ float lds[SEG][32];
  const int tid = threadIdx.x;
  const int jl = tid & 31, seg = tid >> 5;
  const int j = blockIdx.x * 32 + jl;
  const int b = j >> 10, d = j & 1023;
  const size_t base = (size_t)b * NC * Dd + d;
  float s = 0.f;
#pragma unroll 8
  for (int i = 0; i < CPS; ++i) s += a.cs[base + (size_t)(seg * CPS + i) * Dd];
  lds[seg][jl] = s;
  __syncthreads();
  float o = 0.f;
#pragma unroll
  for (int g2 = 0; g2 < SEG; ++g2) { float v = lds[g2][jl]; o += (g2 < seg) ? v : 0.f; }
  __syncthreads();
  float run = o, e = 0.f;
#pragma unroll 8
  for (int i = 0; i < CPS; ++i) {
    const size_t k = base + (size_t)(seg * CPS + i) * Dd;
    float cv = a.cs[k];
    a.off[k] = run;
    e += a.el[k] + run * cv;
    run += cv;
  }
  lds[seg][jl] = e;
  __syncthreads();
  if (seg == 0) {
    float et = 0.f;
#pragma unroll
    for (int g2 = 0; g2 < SEG; ++g2) et += lds[g2][jl];
    a.e[j] = et;
  }
  if (a.last && seg == SEG - 1) a.last[j] = run;
}

// reduce p1/xq partials -> ei, Mv. k2 non-null => cross (ec = fm(k2)*colsum)
__global__ __launch_bounds__(Tb) void t_m8(MA a0, MA a1) {
  const MA a = (blockIdx.z == 0) ? a0 : a1;
  __shared__ float le[SEG][32], lmn[SEG][32], lmx[SEG][32];
  const int tid = threadIdx.x;
  const int jl = tid & 31, seg = tid >> 5;
  const int j = blockIdx.x * 32 + jl;
  const int b = j >> 10, d = j & 1023;
  const size_t base = (size_t)b * NC * Dd + d;
  float ec = 0.f, mn = BIG, mx = 0.f;
#pragma unroll 8
  for (int i = 0; i < CPS; ++i) {
    const size_t k = base + (size_t)(seg * CPS + i) * Dd;
    ec += a.pe[k];
    mn = fminf(mn, a.pmn[k]);
    mx = fmaxf(mx, a.pmx[k]);
  }
  le[seg][jl] = ec; lmn[seg][jl] = mn; lmx[seg][jl] = mx;
  __syncthreads();
  if (seg == 0) {
#pragma unroll
    for (int g2 = 1; g2 < SEG; ++g2) {
      ec += le[g2][jl];
      mn = fminf(mn, lmn[g2][jl]);
      mx = fmaxf(mx, lmx[g2][jl]);
    }
    if (a.k2) ec *= fm_act(a.k2[j]);
    const float e2 = ec * INV_SCALE;
    a.ei[j] = e2;
    a.Mv[j] = (ec >= 0.f) ? e2 * mx : e2 * mn;
  }
}

// reduce partials -> sum (recip=0) or 1/sum (recip=1)
__global__ __launch_bounds__(Tb) void t_red8(RA a0, RA a1) {
  const RA a = (blockIdx.z == 0) ? a0 : a1;
  __shared__ float lds[SEG][32];
  const int tid = threadIdx.x;
  const int jl = tid & 31, seg = tid >> 5;
  const int j = blockIdx.x * 32 + jl;
  const int b = j >> 10, d = j & 1023;
  const size_t base = (size_t)b * NC * Dd + d;
  float s = 0.f;
#pragma unroll 8
  for (int i = 0; i < CPS; ++i) s += a.pp[base + (size_t)(seg * CPS + i) * Dd];
  lds[seg][jl] = s;
  __syncthreads();
  if (seg == 0) {
#pragma unroll
    for (int g2 = 1; g2 < SEG; ++g2) s += lds[g2][jl];
    a.outv[j] = a.recip ? 1.0f / s : s;
  }
}

// out[b,o] = (pooled[b,:]/S) @ Wc + bc
__global__ __launch_bounds__(Tb) void k_final(const float* __restrict__ pooled, const float* __restrict__ Wc,
    const float* __restrict__ bc, float* __restrict__ out) {
  const int b = blockIdx.x, t = threadIdx.x;
  float4 acc = ld4(pooled, (size_t)b * D4 + t);
  float4 w0 = ld4(Wc, 2 * t), w1 = ld4(Wc, 2 * t + 1);
  float s0 = acc.x * w0.x + acc.y * w0.z + acc.z * w1.x + acc.w * w1.z;
  float s1 = acc.x * w0.y + acc.y * w0.w + acc.z * w1.y + acc.w * w1.w;
  s0 = blockSum(s0);
  s1 = blockSum(s1);
  if (t == 0) {
    out[b * 2 + 0] = s0 * (1.0f / Ss) + bc[0];
    out[b * 2 + 1] = s1 * (1.0f / Ss) + bc[1];
  }
}

}  // namespace

extern "C" void kernel_launch(void* const* d_in, const int* in_sizes, int n_in,
                              void* d_out, int out_size, void* d_ws, size_t ws_size,
                              hipStream_t stream) {
  (void)in_sizes; (void)n_in; (void)out_size; (void)ws_size;
  const int* src = (const int*)d_in[0];
  const int* trg = (const int*)d_in[1];
  const float* emb = (const float*)d_in[2];
  const float* enc_g = (const float*)d_in[3];
  const float* enc_b = (const float*)d_in[4];
  const float* dec_ng = (const float*)d_in[5];
  const float* dec_nb = (const float*)d_in[6];
  const float* dec_tg = (const float*)d_in[7];
  const float* dec_tb = (const float*)d_in[8];
  const float* Wc = (const float*)d_in[9];
  const float* bc = (const float*)d_in[10];
  float* out = (float*)d_out;

  float* ws = (float*)d_ws;
  const size_t TEN = (size_t)Bb * Ss * Dd;      // 16.7M floats
  const size_t MM = (size_t)Bb * NC * Dd;       // 2.1M floats
  float* A0 = ws;                                // encoder tensor
  float* A1 = A0 + TEN;                          // decoder tensor
  float* p = A1 + TEN;
  float* csE = p; p += MM;  float* elE = p; p += MM;  float* offE = p; p += MM;
  float* peE = p; p += MM;  float* pmnE = p; p += MM; float* pmxE = p; p += MM;
  float* psE = p; p += MM;
  float* csD = p; p += MM;  float* elD = p; p += MM;  float* offD = p; p += MM;
  float* peD = p; p += MM;  float* pmnD = p; p += MM; float* pmxD = p; p += MM;
  float* psD = p; p += MM;
  const int BD = Bb * Dd;
  float* e0E = p; p += BD;  float* e1E = p; p += BD;
  float* e0D = p; p += BD;  float* e1D = p; p += BD;
  float* eiE = p; p += BD;  float* MvE = p; p += BD;  float* rdvE = p; p += BD;
  float* eiD = p; p += BD;  float* MvD = p; p += BD;  float* rdvD = p; p += BD;
  float* ectx = p; p += BD; float* v2 = p; p += BD;   float* pooled = p; p += BD;

  const dim3 g2(NC, Bb, 2), g1(NC, Bb, 1);
  const dim3 t2(BD / 32, 1, 2), t1(BD / 32, 1, 1);

  // ========== encoder L1 || decoder L1 (independent, z-merged) ==========
  k_gather<<<g2, Tb, 0, stream>>>(GA{src, A0, csE, elE}, GA{trg, A1, csD, elD}, emb);
  t_scan8<<<t2, Tb, 0, stream>>>(SA{csE, elE, offE, e0E, nullptr}, SA{csD, elD, offD, e0D, nullptr});
  k_p1<<<g2, Tb, 0, stream>>>(PA{A0, e0E, offE, peE, pmnE, pmxE}, PA{A1, e0D, offD, peD, pmnD, pmxD});
  t_m8<<<t2, Tb, 0, stream>>>(MA{peE, pmnE, pmxE, nullptr, eiE, MvE}, MA{peD, pmnD, pmxD, nullptr, eiD, MvD});
  k_p2<<<g2, Tb, 0, stream>>>(QA{A0, e0E, eiE, MvE, psE}, QA{A1, e0D, eiD, MvD, psD});
  t_red8<<<t2, Tb, 0, stream>>>(RA{psE, rdvE, 1}, RA{psD, rdvD, 1});
  // enc L1 LN (emits cs/el for enc L2 scan); dec L1 self LN (emits cross-attn qf partials)
  k_ln<<<g2, Tb, 0, stream>>>(
      LA{A0, e0E, e0E, e0E, nullptr, eiE, MvE, rdvE, enc_g, enc_b, csE, elE, nullptr, nullptr, nullptr},
      LA{A1, e0D, e0D, e0D, nullptr, eiD, MvD, rdvD, dec_ng, dec_nb, nullptr, nullptr, peD, pmnD, pmxD});

  // ========== encoder L2 ==========
  t_scan8<<<t1, Tb, 0, stream>>>(SA{csE, elE, offE, e1E, ectx}, SA{csE, elE, offE, e1E, ectx});
  k_p1<<<g1, Tb, 0, stream>>>(PA{A0, nullptr, offE, peE, pmnE, pmxE}, PA{A0, nullptr, offE, peE, pmnE, pmxE});
  t_m8<<<t1, Tb, 0, stream>>>(MA{peE, pmnE, pmxE, nullptr, eiE, MvE}, MA{peE, pmnE, pmxE, nullptr, eiE, MvE});
  k_p2<<<g1, Tb, 0, stream>>>(QA{A0, nullptr, eiE, MvE, psE}, QA{A0, nullptr, eiE, MvE, psE});
  t_red8<<<t1, Tb, 0, stream>>>(RA{psE, rdvE, 1}, RA{psE, rdvE, 1});
  k_ln<<<g1, Tb, 0, stream>>>(
      LA{A0, nullptr, e1E, nullptr, nullptr, eiE, MvE, rdvE, enc_g + Dd, enc_b + Dd, csE, nullptr, nullptr, nullptr, nullptr},
      LA{A0, nullptr, e1E, nullptr, nullptr, eiE, MvE, rdvE, enc_g + Dd, enc_b + Dd, csE, nullptr, nullptr, nullptr, nullptr});
  t_red8<<<t1, Tb, 0, stream>>>(RA{csE, v2, 0}, RA{csE, v2, 0});  // v2 = colsum(enc_out)

  // ========== decoder cross 1 ==========
  t_m8<<<t1, Tb, 0, stream>>>(MA{peD, pmnD, pmxD, ectx, eiD, MvD}, MA{peD, pmnD, pmxD, ectx, eiD, MvD});
  k_p2<<<g1, Tb, 0, stream>>>(QA{A1, nullptr, eiD, MvD, psD}, QA{A1, nullptr, eiD, MvD, psD});
  t_red8<<<t1, Tb, 0, stream>>>(RA{psD, rdvD, 1}, RA{psD, rdvD, 1});
  k_ln<<<g1, Tb, 0, stream>>>(
      LA{A1, nullptr, nullptr, nullptr, v2, eiD, MvD, rdvD, dec_tg, dec_tb, csD, elD, nullptr, nullptr, nullptr},
      LA{A1, nullptr, nullptr, nullptr, v2, eiD, MvD, rdvD, dec_tg, dec_tb, csD, elD, nullptr, nullptr, nullptr});

  // ========== decoder L2 self ==========
  t_scan8<<<t1, Tb, 0, stream>>>(SA{csD, elD, offD, e1D, nullptr}, SA{csD, elD, offD, e1D, nullptr});
  k_p1<<<g1, Tb, 0, stream>>>(PA{A1, nullptr, offD, peD, pmnD, pmxD}, PA{A1, nullptr, offD, peD, pmnD, pmxD});
  t_m8<<<t1, Tb, 0, stream>>>(MA{peD, pmnD, pmxD, nullptr, eiD, MvD}, MA{peD, pmnD, pmxD, nullptr, eiD, MvD});
  k_p2<<<g1, Tb, 0, stream>>>(QA{A1, nullptr, eiD, MvD, psD}, QA{A1, nullptr, eiD, MvD, psD});
  t_red8<<<t1, Tb, 0, stream>>>(RA{psD, rdvD, 1}, RA{psD, rdvD, 1});
  k_ln<<<g1, Tb, 0, stream>>>(
      LA{A1, nullptr, e1D, nullptr, nullptr, eiD, MvD, rdvD, dec_ng + Dd, dec_nb + Dd, nullptr, nullptr, peD, pmnD, pmxD},
      LA{A1, nullptr, e1D, nullptr, nullptr, eiD, MvD, rdvD, dec_ng + Dd, dec_nb + Dd, nullptr, nullptr, peD, pmnD, pmxD});

  // ========== decoder cross 2 ==========
  t_m8<<<t1, Tb, 0, stream>>>(MA{peD, pmnD, pmxD, ectx, eiD, MvD}, MA{peD, pmnD, pmxD, ectx, eiD, MvD});
  k_p2<<<g1, Tb, 0, stream>>>(QA{A1, nullptr, eiD, MvD, psD}, QA{A1, nullptr, eiD, MvD, psD});
  t_red8<<<t1, Tb, 0, stream>>>(RA{psD, rdvD, 1}, RA{psD, rdvD, 1});
  k_ln<<<g1, Tb, 0, stream>>>(
      LA{A1, nullptr, nullptr, nullptr, v2, eiD, MvD, rdvD, dec_tg + Dd, dec_tb + Dd, csD, nullptr, nullptr, nullptr, nullptr},
      LA{A1, nullptr, nullptr, nullptr, v2, eiD, MvD, rdvD, dec_tg + Dd, dec_tb + Dd, csD, nullptr, nullptr, nullptr, nullptr});

  // ========== pooled + classifier ==========
  t_red8<<<t1, Tb, 0, stream>>>(RA{csD, pooled, 0}, RA{csD, pooled, 0});
  k_final<<<Bb, Tb, 0, stream>>>(pooled, Wc, bc, out);
}

// Round 6
// 454.225 us; speedup vs baseline: 2.6393x; 1.0489x over previous
//
#include <hip/hip_runtime.h>
#include <math.h>

namespace {

constexpr int Bb = 8;
constexpr int Ss = 2048;
constexpr int Dd = 1024;
constexpr int D4 = Dd / 4;        // float4 per row
constexpr int NC = 256;           // s-chunks
constexpr int Sc2 = Ss / NC;      // 8 rows per chunk
constexpr int Tb = 256;
constexpr int SEG = 8;            // segments per column in tiny reducers
constexpr int CPS = NC / SEG;     // 32 chunks per segment
constexpr float INV_SCALE = 0.03125f;  // 1/sqrt(1024)
constexpr float BIG = 3.0e38f;

// branch-free erf, Abramowitz-Stegun 7.1.26, |abs err| <= 1.5e-7
__device__ __forceinline__ float fast_erf(float z) {
  float az = fabsf(z);
  float t = __builtin_amdgcn_rcpf(fmaf(0.3275911f, az, 1.0f));
  float p = fmaf(1.061405429f, t, -1.453152027f);
  p = fmaf(p, t, 1.421413741f);
  p = fmaf(p, t, -0.284496736f);
  p = fmaf(p, t, 0.254829592f);
  p *= t;
  float e = __expf(-az * az);
  float r = fmaf(-p, e, 1.0f);
  return copysignf(r, z);
}
// gelu(x, exact) + 1
__device__ __forceinline__ float fm_act(float x) {
  return fmaf(0.5f * x, 1.0f + fast_erf(x * 0.70710678118654752f), 1.0f);
}

__device__ __forceinline__ float4 f4(float v) { return make_float4(v, v, v, v); }
__device__ __forceinline__ float4 add4(float4 a, float4 b) {
  return make_float4(a.x + b.x, a.y + b.y, a.z + b.z, a.w + b.w);
}
__device__ __forceinline__ float4 mul4(float4 a, float4 b) {
  return make_float4(a.x * b.x, a.y * b.y, a.z * b.z, a.w * b.w);
}
__device__ __forceinline__ float4 fma4(float4 a, float4 b, float4 c) {
  return make_float4(fmaf(a.x, b.x, c.x), fmaf(a.y, b.y, c.y), fmaf(a.z, b.z, c.z), fmaf(a.w, b.w, c.w));
}
__device__ __forceinline__ float4 min4(float4 a, float4 b) {
  return make_float4(fminf(a.x, b.x), fminf(a.y, b.y), fminf(a.z, b.z), fminf(a.w, b.w));
}
__device__ __forceinline__ float4 max4(float4 a, float4 b) {
  return make_float4(fmaxf(a.x, b.x), fmaxf(a.y, b.y), fmaxf(a.z, b.z), fmaxf(a.w, b.w));
}
__device__ __forceinline__ float4 fm4(float4 x) {
  return make_float4(fm_act(x.x), fm_act(x.y), fm_act(x.z), fm_act(x.w));
}
__device__ __forceinline__ float4 ld4(const float* p, size_t j4) {
  return reinterpret_cast<const float4*>(p)[j4];
}
__device__ __forceinline__ void st4(float* p, size_t j4, float4 v) {
  reinterpret_cast<float4*>(p)[j4] = v;
}
__device__ __forceinline__ float4 pexp4(float4 ei, float4 qf, float4 M) {
  return make_float4(__expf(fmaf(ei.x, qf.x, -M.x)), __expf(fmaf(ei.y, qf.y, -M.y)),
                     __expf(fmaf(ei.z, qf.z, -M.z)), __expf(fmaf(ei.w, qf.w, -M.w)));
}

__device__ __forceinline__ float blockSum(float v) {
  __shared__ float wsm[Tb / 64];
  for (int off = 32; off > 0; off >>= 1) v += __shfl_down(v, off, 64);
  const int lane = threadIdx.x & 63;
  const int w = threadIdx.x >> 6;
  __syncthreads();
  if (lane == 0) wsm[w] = v;
  __syncthreads();
  return wsm[0] + wsm[1] + wsm[2] + wsm[3];
}

// ---------- arg structs (z-mergeable kernels pick by blockIdx.z) ----------
struct GA { const int* tok; float* X; float* cs; float* el; };
struct SA { const float* cs; const float* el; float* off; float* e; float* last; };
struct PA { const float* X; const float* qs; const float* off; float* pe; float* pmn; float* pmx; };
struct MA { const float* pe; const float* pmn; const float* pmx; const float* k2; float* ei; float* Mv; };
struct QA { const float* X; const float* qs; const float* ei; const float* Mv; float* ps; };
struct RA { const float* pp; float* outv; int recip; };
struct LA { float* X; const float* qs; const float* vs; const float* rs; const float* ml;
            const float* ei; const float* Mv; const float* rdv; const float* g; const float* bt;
            float* cs; float* el; float* xe; float* xn; float* xx; int wout; };

// ---------- big column-pass kernels: grid(NC, B, nz), 256 thr, thread t = float4 at d=4t ----------

// gather emb rows + chunk colsums + local gds partial
__global__ __launch_bounds__(Tb) void k_gather(GA a0, GA a1, const float* __restrict__ emb) {
  const GA a = (blockIdx.z == 0) ? a0 : a1;
  const int t = threadIdx.x, c = blockIdx.x, b = blockIdx.y;
  const int* tp = a.tok + b * Ss + c * Sc2;
  float4* xp = reinterpret_cast<float4*>(a.X) + ((size_t)(b * Ss + c * Sc2)) * D4 + t;
  const float4* ep = reinterpret_cast<const float4*>(emb);
  float4 run = f4(0.f), e = f4(0.f);
#pragma unroll
  for (int i = 0; i < Sc2; ++i) {
    float4 v = ep[(size_t)tp[i] * D4 + t];
    xp[(size_t)i * D4] = v;
    run = add4(run, v);
    e = fma4(v, run, e);
  }
  const size_t idx = ((size_t)b * NC + c) * D4 + t;
  st4(a.cs, idx, run);
  st4(a.el, idx, e);
}

// self-attn p1: ctx from off + running sum; partial ecol & qf min/max per chunk
__global__ __launch_bounds__(Tb) void k_p1(PA a0, PA a1) {
  const PA a = (blockIdx.z == 0) ? a0 : a1;
  const int t = threadIdx.x, c = blockIdx.x, b = blockIdx.y;
  const size_t idx = ((size_t)b * NC + c) * D4 + t;
  float4 run = ld4(a.off, idx);
  const float4 q4 = a.qs ? ld4(a.qs, (size_t)b * D4 + t) : f4(1.f);
  const float4* xp = reinterpret_cast<const float4*>(a.X) + ((size_t)(b * Ss + c * Sc2)) * D4 + t;
  float4 e = f4(0.f), mn = f4(BIG), mx = f4(0.f);
#pragma unroll
  for (int i = 0; i < Sc2; ++i) {
    float4 x = xp[(size_t)i * D4];
    run = add4(run, x);
    float4 qf = fm4(mul4(q4, x));
    float4 kf = fm4(run);
    e = fma4(qf, kf, e);
    mn = min4(mn, qf);
    mx = max4(mx, qf);
  }
  st4(a.pe, idx, e);
  st4(a.pmn, idx, mn);
  st4(a.pmx, idx, mx);
}

// p2: partial sumexp per chunk (self [qs] and cross [qs=null])
__global__ __launch_bounds__(Tb) void k_p2(QA a0, QA a1) {
  const QA a = (blockIdx.z == 0) ? a0 : a1;
  const int t = threadIdx.x, c = blockIdx.x, b = blockIdx.y;
  const size_t j4 = (size_t)b * D4 + t;
  const float4 q4 = a.qs ? ld4(a.qs, j4) : f4(1.f);
  const float4 e4 = ld4(a.ei, j4);
  const float4 M4 = ld4(a.Mv, j4);
  const float4* xp = reinterpret_cast<const float4*>(a.X) + ((size_t)(b * Ss + c * Sc2)) * D4 + t;
  float4 s = f4(0.f);
#pragma unroll
  for (int i = 0; i < Sc2; ++i) {
    float4 x = xp[(size_t)i * D4];
    float4 qf = fm4(mul4(q4, x));
    s = add4(s, pexp4(e4, qf, M4));
  }
  st4(a.ps, ((size_t)b * NC + c) * D4 + t, s);
}

// fused softmax-apply + residual + LayerNorm (in place, store optional via wout),
// optional chunk colsum/gds partials, optional cross-attn qf partials of the output.
__global__ __launch_bounds__(Tb) void k_ln(LA a0, LA a1) {
  const LA a = (blockIdx.z == 0) ? a0 : a1;
  __shared__ float red[Sc2][Tb];
  __shared__ float mu_s[Sc2], inv_s[Sc2];
  const int t = threadIdx.x, c = blockIdx.x, b = blockIdx.y;
  float4* xp = reinterpret_cast<float4*>(a.X) + ((size_t)(b * Ss + c * Sc2)) * D4 + t;
  const size_t j4 = (size_t)b * D4 + t;
  const float4 e4 = ld4(a.ei, j4), M4 = ld4(a.Mv, j4), rv4 = ld4(a.rdv, j4);
  const float4 q4 = a.qs ? ld4(a.qs, j4) : f4(1.f);
  const float4 vs4 = a.vs ? ld4(a.vs, j4) : f4(1.f);
  const float4 ml4 = a.ml ? ld4(a.ml, j4) : f4(1.f);
  const float4 rs4 = a.rs ? ld4(a.rs, j4) : f4(1.f);
  float4 vals[Sc2];
#pragma unroll
  for (int i = 0; i < Sc2; ++i) {
    float4 x = xp[(size_t)i * D4];
    float4 qf = fm4(mul4(q4, x));
    float4 p = mul4(pexp4(e4, qf, M4), rv4);
    float4 v = a.ml ? mul4(p, ml4) : mul4(p, mul4(vs4, x));
    float4 val = add4(v, mul4(rs4, x));
    vals[i] = val;
    red[i][t] = val.x + val.y + val.z + val.w;
  }
  __syncthreads();
  const int lane = t & 63, w = t >> 6;
#pragma unroll
  for (int rr = 0; rr < Sc2 / 4; ++rr) {
    const int row = w * (Sc2 / 4) + rr;
    float s = red[row][lane] + red[row][lane + 64] + red[row][lane + 128] + red[row][lane + 192];
    for (int off = 32; off > 0; off >>= 1) s += __shfl_down(s, off, 64);
    if (lane == 0) mu_s[row] = s * (1.0f / Dd);
  }
  __syncthreads();
#pragma unroll
  for (int i = 0; i < Sc2; ++i) {
    const float m = mu_s[i];
    float4 vv = vals[i];
    float aa = vv.x - m, b2 = vv.y - m, c2 = vv.z - m, d2 = vv.w - m;
    red[i][t] = aa * aa + b2 * b2 + c2 * c2 + d2 * d2;
  }
  __syncthreads();
#pragma unroll
  for (int rr = 0; rr < Sc2 / 4; ++rr) {
    const int row = w * (Sc2 / 4) + rr;
    float s = red[row][lane] + red[row][lane + 64] + red[row][lane + 128] + red[row][lane + 192];
    for (int off = 32; off > 0; off >>= 1) s += __shfl_down(s, off, 64);
    if (lane == 0) inv_s[row] = rsqrtf(s * (1.0f / Dd) + 1e-5f);
  }
  __syncthreads();
  const float4 g4 = ld4(a.g, t), b4 = ld4(a.bt, t);
  float4 run = f4(0.f), e = f4(0.f);
  float4 xs = f4(0.f), xmn = f4(BIG), xmx = f4(0.f);
#pragma unroll
  for (int i = 0; i < Sc2; ++i) {
    const float m = mu_s[i], inv = inv_s[i];
    float4 vv = vals[i];
    float4 y;
    y.x = fmaf((vv.x - m) * inv, g4.x, b4.x);
    y.y = fmaf((vv.y - m) * inv, g4.y, b4.y);
    y.z = fmaf((vv.z - m) * inv, g4.z, b4.z);
    y.w = fmaf((vv.w - m) * inv, g4.w, b4.w);
    if (a.wout) xp[(size_t)i * D4] = y;
    if (a.cs) {
      run = add4(run, y);
      if (a.el) e = fma4(y, run, e);
    }
    if (a.xe) {
      float4 qfy = fm4(y);
      xs = add4(xs, qfy);
      xmn = min4(xmn, qfy);
      xmx = max4(xmx, qfy);
    }
  }
  const size_t idx = ((size_t)b * NC + c) * D4 + t;
  if (a.cs) st4(a.cs, idx, run);
  if (a.el) st4(a.el, idx, e);
  if (a.xe) {
    st4(a.xe, idx, xs);
    st4(a.xn, idx, xmn);
    st4(a.xx, idx, xmx);
  }
}

// ---------- tiny reducers: grid(BD/32, 1, nz), 256 thr = 32 columns x 8 segments ----------

__global__ __launch_bounds__(Tb) void t_scan8(SA a0, SA a1) {
  const SA a = (blockIdx.z == 0) ? a0 : a1;
  __shared__ float lds[SEG][32];
  const int tid = threadIdx.x;
  const int jl = tid & 31, seg = tid >> 5;
  const int j = blockIdx.x * 32 + jl;
  const int b = j >> 10, d = j & 1023;
  const size_t base = (size_t)b * NC * Dd + d;
  float s = 0.f;
#pragma unroll 8
  for (int i = 0; i < CPS; ++i) s += a.cs[base + (size_t)(seg * CPS + i) * Dd];
  lds[seg][jl] = s;
  __syncthreads();
  float o = 0.f;
#pragma unroll
  for (int g2 = 0; g2 < SEG; ++g2) { float v = lds[g2][jl]; o += (g2 < seg) ? v : 0.f; }
  __syncthreads();
  float run = o, e = 0.f;
#pragma unroll 8
  for (int i = 0; i < CPS; ++i) {
    const size_t k = base + (size_t)(seg * CPS + i) * Dd;
    float cv = a.cs[k];
    a.off[k] = run;
    e += a.el[k] + run * cv;
    run += cv;
  }
  lds[seg][jl] = e;
  __syncthreads();
  if (seg == 0) {
    float et = 0.f;
#pragma unroll
    for (int g2 = 0; g2 < SEG; ++g2) et += lds[g2][jl];
    a.e[j] = et;
  }
  if (a.last && seg == SEG - 1) a.last[j] = run;
}

// reduce p1/xq partials -> ei, Mv. k2 non-null => cross (ec = fm(k2)*colsum)
__global__ __launch_bounds__(Tb) void t_m8(MA a0, MA a1) {
  const MA a = (blockIdx.z == 0) ? a0 : a1;
  __shared__ float le[SEG][32], lmn[SEG][32], lmx[SEG][32];
  const int tid = threadIdx.x;
  const int jl = tid & 31, seg = tid >> 5;
  const int j = blockIdx.x * 32 + jl;
  const int b = j >> 10, d = j & 1023;
  const size_t base = (size_t)b * NC * Dd + d;
  float ec = 0.f, mn = BIG, mx = 0.f;
#pragma unroll 8
  for (int i = 0; i < CPS; ++i) {
    const size_t k = base + (size_t)(seg * CPS + i) * Dd;
    ec += a.pe[k];
    mn = fminf(mn, a.pmn[k]);
    mx = fmaxf(mx, a.pmx[k]);
  }
  le[seg][jl] = ec; lmn[seg][jl] = mn; lmx[seg][jl] = mx;
  __syncthreads();
  if (seg == 0) {
#pragma unroll
    for (int g2 = 1; g2 < SEG; ++g2) {
      ec += le[g2][jl];
      mn = fminf(mn, lmn[g2][jl]);
      mx = fmaxf(mx, lmx[g2][jl]);
    }
    if (a.k2) ec *= fm_act(a.k2[j]);
    const float e2 = ec * INV_SCALE;
    a.ei[j] = e2;
    a.Mv[j] = (ec >= 0.f) ? e2 * mx : e2 * mn;
  }
}

// reduce partials -> sum (recip=0) or 1/sum (recip=1)
__global__ __launch_bounds__(Tb) void t_red8(RA a0, RA a1) {
  const RA a = (blockIdx.z == 0) ? a0 : a1;
  __shared__ float lds[SEG][32];
  const int tid = threadIdx.x;
  const int jl = tid & 31, seg = tid >> 5;
  const int j = blockIdx.x * 32 + jl;
  const int b = j >> 10, d = j & 1023;
  const size_t base = (size_t)b * NC * Dd + d;
  float s = 0.f;
#pragma unroll 8
  for (int i = 0; i < CPS; ++i) s += a.pp[base + (size_t)(seg * CPS + i) * Dd];
  lds[seg][jl] = s;
  __syncthreads();
  if (seg == 0) {
#pragma unroll
    for (int g2 = 1; g2 < SEG; ++g2) s += lds[g2][jl];
    a.outv[j] = a.recip ? 1.0f / s : s;
  }
}

// out[b,o] = (pooled[b,:]/S) @ Wc + bc
__global__ __launch_bounds__(Tb) void k_final(const float* __restrict__ pooled, const float* __restrict__ Wc,
    const float* __restrict__ bc, float* __restrict__ out) {
  const int b = blockIdx.x, t = threadIdx.x;
  float4 acc = ld4(pooled, (size_t)b * D4 + t);
  float4 w0 = ld4(Wc, 2 * t), w1 = ld4(Wc, 2 * t + 1);
  float s0 = acc.x * w0.x + acc.y * w0.z + acc.z * w1.x + acc.w * w1.z;
  float s1 = acc.x * w0.y + acc.y * w0.w + acc.z * w1.y + acc.w * w1.w;
  s0 = blockSum(s0);
  s1 = blockSum(s1);
  if (t == 0) {
    out[b * 2 + 0] = s0 * (1.0f / Ss) + bc[0];
    out[b * 2 + 1] = s1 * (1.0f / Ss) + bc[1];
  }
}

}  // namespace

extern "C" void kernel_launch(void* const* d_in, const int* in_sizes, int n_in,
                              void* d_out, int out_size, void* d_ws, size_t ws_size,
                              hipStream_t stream) {
  (void)in_sizes; (void)n_in; (void)out_size; (void)ws_size;
  const int* src = (const int*)d_in[0];
  const int* trg = (const int*)d_in[1];
  const float* emb = (const float*)d_in[2];
  const float* enc_g = (const float*)d_in[3];
  const float* enc_b = (const float*)d_in[4];
  const float* dec_ng = (const float*)d_in[5];
  const float* dec_nb = (const float*)d_in[6];
  const float* dec_tg = (const float*)d_in[7];
  const float* dec_tb = (const float*)d_in[8];
  const float* Wc = (const float*)d_in[9];
  const float* bc = (const float*)d_in[10];
  float* out = (float*)d_out;

  float* ws = (float*)d_ws;
  const size_t TEN = (size_t)Bb * Ss * Dd;      // 16.7M floats
  const size_t MM = (size_t)Bb * NC * Dd;       // 2.1M floats
  float* A0 = ws;                                // encoder tensor
  float* A1 = A0 + TEN;                          // decoder tensor
  float* p = A1 + TEN;
  float* csE = p; p += MM;  float* elE = p; p += MM;  float* offE = p; p += MM;
  float* peE = p; p += MM;  float* pmnE = p; p += MM; float* pmxE = p; p += MM;
  float* psE = p; p += MM;
  float* csD = p; p += MM;  float* elD = p; p += MM;  float* offD = p; p += MM;
  float* peD = p; p += MM;  float* pmnD = p; p += MM; float* pmxD = p; p += MM;
  float* psD = p; p += MM;
  const int BD = Bb * Dd;
  float* e0E = p; p += BD;  float* e1E = p; p += BD;
  float* e0D = p; p += BD;  float* e1D = p; p += BD;
  float* eiE = p; p += BD;  float* MvE = p; p += BD;  float* rdvE = p; p += BD;
  float* eiD = p; p += BD;  float* MvD = p; p += BD;  float* rdvD = p; p += BD;
  float* ectx = p; p += BD; float* v2 = p; p += BD;   float* pooled = p; p += BD;

  const dim3 g2(NC, Bb, 2), g1(NC, Bb, 1);
  const dim3 t2(BD / 32, 1, 2), t1(BD / 32, 1, 1);

  // ===== L1 stage: encoder L1 || decoder L1 self (independent, z-merged) =====
  k_gather<<<g2, Tb, 0, stream>>>(GA{src, A0, csE, elE}, GA{trg, A1, csD, elD}, emb);
  t_scan8<<<t2, Tb, 0, stream>>>(SA{csE, elE, offE, e0E, nullptr}, SA{csD, elD, offD, e0D, nullptr});
  k_p1<<<g2, Tb, 0, stream>>>(PA{A0, e0E, offE, peE, pmnE, pmxE}, PA{A1, e0D, offD, peD, pmnD, pmxD});
  t_m8<<<t2, Tb, 0, stream>>>(MA{peE, pmnE, pmxE, nullptr, eiE, MvE}, MA{peD, pmnD, pmxD, nullptr, eiD, MvD});
  k_p2<<<g2, Tb, 0, stream>>>(QA{A0, e0E, eiE, MvE, psE}, QA{A1, e0D, eiD, MvD, psD});
  t_red8<<<t2, Tb, 0, stream>>>(RA{psE, rdvE, 1}, RA{psD, rdvD, 1});
  // enc L1 LN (emits cs/el for enc L2 scan); dec L1 self LN (emits cross-attn qf partials)
  k_ln<<<g2, Tb, 0, stream>>>(
      LA{A0, e0E, e0E, e0E, nullptr, eiE, MvE, rdvE, enc_g, enc_b, csE, elE, nullptr, nullptr, nullptr, 1},
      LA{A1, e0D, e0D, e0D, nullptr, eiD, MvD, rdvD, dec_ng, dec_nb, nullptr, nullptr, peD, pmnD, pmxD, 1});

  // ===== enc L2 scan (produces ectx, the only cross-attn K) =====
  t_scan8<<<t1, Tb, 0, stream>>>(SA{csE, elE, offE, e1E, ectx}, SA{csE, elE, offE, e1E, ectx});
  k_p1<<<g1, Tb, 0, stream>>>(PA{A0, nullptr, offE, peE, pmnE, pmxE}, PA{A0, nullptr, offE, peE, pmnE, pmxE});

  // ===== enc L2 self || dec cross-1 (z-merged: Dx1 needs only ectx + xeD) =====
  t_m8<<<t2, Tb, 0, stream>>>(MA{peE, pmnE, pmxE, nullptr, eiE, MvE}, MA{peD, pmnD, pmxD, ectx, eiD, MvD});
  k_p2<<<g2, Tb, 0, stream>>>(QA{A0, nullptr, eiE, MvE, psE}, QA{A1, nullptr, eiD, MvD, psD});
  t_red8<<<t2, Tb, 0, stream>>>(RA{psE, rdvE, 1}, RA{psD, rdvD, 1});
  // enc L2 LN: output tensor is never read -> skip store; emit only colsum partials (v2)
  k_ln<<<g1, Tb, 0, stream>>>(
      LA{A0, nullptr, e1E, nullptr, nullptr, eiE, MvE, rdvE, enc_g + Dd, enc_b + Dd, csE, nullptr, nullptr, nullptr, nullptr, 0},
      LA{A0, nullptr, e1E, nullptr, nullptr, eiE, MvE, rdvE, enc_g + Dd, enc_b + Dd, csE, nullptr, nullptr, nullptr, nullptr, 0});
  t_red8<<<t1, Tb, 0, stream>>>(RA{csE, v2, 0}, RA{csE, v2, 0});  // v2 = colsum(enc_out)

  // ===== dec cross-1 LN (needs v2) =====
  k_ln<<<g1, Tb, 0, stream>>>(
      LA{A1, nullptr, nullptr, nullptr, v2, eiD, MvD, rdvD, dec_tg, dec_tb, csD, elD, nullptr, nullptr, nullptr, 1},
      LA{A1, nullptr, nullptr, nullptr, v2, eiD, MvD, rdvD, dec_tg, dec_tb, csD, elD, nullptr, nullptr, nullptr, 1});

  // ===== dec L2 self =====
  t_scan8<<<t1, Tb, 0, stream>>>(SA{csD, elD, offD, e1D, nullptr}, SA{csD, elD, offD, e1D, nullptr});
  k_p1<<<g1, Tb, 0, stream>>>(PA{A1, nullptr, offD, peD, pmnD, pmxD}, PA{A1, nullptr, offD, peD, pmnD, pmxD});
  t_m8<<<t1, Tb, 0, stream>>>(MA{peD, pmnD, pmxD, nullptr, eiD, MvD}, MA{peD, pmnD, pmxD, nullptr, eiD, MvD});
  k_p2<<<g1, Tb, 0, stream>>>(QA{A1, nullptr, eiD, MvD, psD}, QA{A1, nullptr, eiD, MvD, psD});
  t_red8<<<t1, Tb, 0, stream>>>(RA{psD, rdvD, 1}, RA{psD, rdvD, 1});
  k_ln<<<g1, Tb, 0, stream>>>(
      LA{A1, nullptr, e1D, nullptr, nullptr, eiD, MvD, rdvD, dec_ng + Dd, dec_nb + Dd, nullptr, nullptr, peD, pmnD, pmxD, 1},
      LA{A1, nullptr, e1D, nullptr, nullptr, eiD, MvD, rdvD, dec_ng + Dd, dec_nb + Dd, nullptr, nullptr, peD, pmnD, pmxD, 1});

  // ===== dec cross-2 =====
  t_m8<<<t1, Tb, 0, stream>>>(MA{peD, pmnD, pmxD, ectx, eiD, MvD}, MA{peD, pmnD, pmxD, ectx, eiD, MvD});
  k_p2<<<g1, Tb, 0, stream>>>(QA{A1, nullptr, eiD, MvD, psD}, QA{A1, nullptr, eiD, MvD, psD});
  t_red8<<<t1, Tb, 0, stream>>>(RA{psD, rdvD, 1}, RA{psD, rdvD, 1});
  // final LN: output tensor never read -> skip store; emit only colsum partials (pooled)
  k_ln<<<g1, Tb, 0, stream>>>(
      LA{A1, nullptr, nullptr, nullptr, v2, eiD, MvD, rdvD, dec_tg + Dd, dec_tb + Dd, csD, nullptr, nullptr, nullptr, nullptr, 0},
      LA{A1, nullptr, nullptr, nullptr, v2, eiD, MvD, rdvD, dec_tg + Dd, dec_tb + Dd, csD, nullptr, nullptr, nullptr, nullptr, 0});

  // ===== pooled + classifier =====
  t_red8<<<t1, Tb, 0, stream>>>(RA{csD, pooled, 0}, RA{csD, pooled, 0});
  k_final<<<Bb, Tb, 0, stream>>>(pooled, Wc, bc, out);
}